// Round 1
// baseline (9797.960 us; speedup 1.0000x reference)
//
#include <hip/hip_runtime.h>
#include <cstdint>
#include <cstddef>

#define B_   2
#define P_   8192
#define C_   128
#define NVOX 24
#define N3   (NVOX*NVOX*NVOX)   // 13824

// ---------------- voxel ids ----------------
__global__ __launch_bounds__(256)
void k_vid(const float* __restrict__ pcl, int* __restrict__ vid)
{
    int b = blockIdx.x;
    const float* pb = pcl + (size_t)b * P_ * 3;
    float mn[3] = {3e38f, 3e38f, 3e38f};
    float mx[3] = {-3e38f, -3e38f, -3e38f};
    for (int p = threadIdx.x; p < P_; p += 256) {
        #pragma unroll
        for (int d = 0; d < 3; ++d) {
            float v = pb[p*3 + d];
            mn[d] = fminf(mn[d], v);
            mx[d] = fmaxf(mx[d], v);
        }
    }
    __shared__ float red[6][256];
    #pragma unroll
    for (int d = 0; d < 3; ++d) { red[d][threadIdx.x] = mn[d]; red[3+d][threadIdx.x] = mx[d]; }
    __syncthreads();
    for (int s = 128; s > 0; s >>= 1) {
        if (threadIdx.x < (unsigned)s) {
            #pragma unroll
            for (int d = 0; d < 3; ++d) {
                red[d][threadIdx.x]   = fminf(red[d][threadIdx.x],   red[d][threadIdx.x + s]);
                red[3+d][threadIdx.x] = fmaxf(red[3+d][threadIdx.x], red[3+d][threadIdx.x + s]);
            }
        }
        __syncthreads();
    }
    float mn0 = red[0][0], mn1 = red[1][0], mn2 = red[2][0];
    float dd0 = red[3][0] - mn0 + 1e-9f;
    float dd1 = red[4][0] - mn1 + 1e-9f;
    float dd2 = red[5][0] - mn2 + 1e-9f;
    for (int p = threadIdx.x; p < P_; p += 256) {
        float fx = (pb[p*3+0] - mn0) / dd0 * 24.0f;
        float fy = (pb[p*3+1] - mn1) / dd1 * 24.0f;
        float fz = (pb[p*3+2] - mn2) / dd2 * 24.0f;
        int ix = (int)floorf(fx); ix = ix < 0 ? 0 : (ix > 23 ? 23 : ix);
        int iy = (int)floorf(fy); iy = iy < 0 ? 0 : (iy > 23 ? 23 : iy);
        int iz = (int)floorf(fz); iz = iz < 0 ? 0 : (iz > 23 ? 23 : iz);
        vid[b*P_ + p] = ix*576 + iy*24 + iz;
    }
}

// ---------------- scatter-add point features -> (B, N3, C) ----------------
__global__ __launch_bounds__(256)
void k_scatter(const float* __restrict__ feat, const int* __restrict__ vid,
               float* __restrict__ meshS)
{
    int g = blockIdx.x*256 + threadIdx.x;      // B*P*C = 2,097,152
    int c  = g & (C_-1);
    int bp = g >> 7;
    int v  = vid[bp];
    int b  = bp >> 13;                          // P = 2^13
    atomicAdd(&meshS[((size_t)b*N3 + v)*C_ + c], feat[g]);
}

// ---------------- transpose (B,N3,C) -> (B,C,N3) ----------------
__global__ __launch_bounds__(256)
void k_transpose(const float* __restrict__ meshS, float* __restrict__ meshT)
{
    __shared__ float tile[32][33];
    int b  = blockIdx.z;
    int v0 = blockIdx.x * 32;   // 432 tiles
    int c0 = blockIdx.y * 32;   // 4 tiles
    int i = threadIdx.x >> 5;   // 0..7
    int j = threadIdx.x & 31;
    #pragma unroll
    for (int r = 0; r < 32; r += 8)
        tile[i+r][j] = meshS[((size_t)b*N3 + v0 + i + r)*C_ + c0 + j];
    __syncthreads();
    #pragma unroll
    for (int r = 0; r < 32; r += 8)
        meshT[((size_t)b*C_ + c0 + i + r)*N3 + v0 + j] = tile[j][i+r];
}

// ---------------- implicit-GEMM direct conv ----------------
// in: (B, CIN, IND^3); W: (COUT, CIN*KD^3) row-major (native torch/jax layout)
// out: (B, cout, OUTD^3).  BM=128, BN=64, BK=16, thread tile 8x4, 256 threads.
template<int CIN, int KD, int STRIDE, int IND, int OUTD, bool RELU, bool ATOMIC>
__global__ __launch_bounds__(256)
void k_conv(const float* __restrict__ in, const float* __restrict__ W,
            const float* __restrict__ bias, float* __restrict__ out, int cout)
{
    constexpr int K3   = KD*KD*KD;
    constexpr int IND2 = IND*IND;
    constexpr int IND3 = IND2*IND;
    constexpr int OUT2 = OUTD*OUTD;
    constexpr int OUT3 = OUT2*OUTD;
    constexpr int KTOT = CIN*K3;
    constexpr int NCH  = KTOT/16;

    const int tid  = threadIdx.x;
    const int mIdx = tid >> 4;
    const int nIdx = tid & 15;

    const int n0g = blockIdx.x * 64;
    const int b   = n0g / OUT3;
    const int s0  = n0g % OUT3;
    const int co0 = blockIdx.y * 128;

    int c0 = 0, c1 = NCH;
    if (ATOMIC) {
        int per = (NCH + (int)gridDim.z - 1) / (int)gridDim.z;
        c0 = blockIdx.z * per;
        c1 = min(NCH, c0 + per);
    }

    __shared__ float As[16][128];
    __shared__ float Bs[16][64];

    // staging decode (one n per thread for B; one row-half for A)
    const int nnS = tid & 63;
    const int kkG = (tid >> 6) << 2;       // 0,4,8,12
    int sS = s0 + nnS;
    int xS = sS / OUT2;
    int yS = (sS / OUTD) % OUTD;
    int zS = sS % OUTD;
    const float* inb = in + (size_t)b*CIN*IND3
                          + (xS*STRIDE)*IND2 + (yS*STRIDE)*IND + (zS*STRIDE);

    const int arow = tid >> 1;
    const int acol = (tid & 1) * 8;
    const float* Wr = W + (size_t)(co0 + arow)*KTOT + acol;

    float acc[8][4];
    #pragma unroll
    for (int i = 0; i < 8; ++i)
        #pragma unroll
        for (int j = 0; j < 4; ++j) acc[i][j] = 0.f;

    for (int c = c0; c < c1; ++c) {
        const int k0 = c*16;
        float4 a0 = *(const float4*)(Wr + k0);
        float4 a1 = *(const float4*)(Wr + k0 + 4);
        float bv[4];
        #pragma unroll
        for (int t = 0; t < 4; ++t) {
            int k  = k0 + kkG + t;
            int ci = k / K3;
            int r  = k - ci*K3;
            int kd = r / (KD*KD);
            int r2 = r - kd*(KD*KD);
            int kh = r2 / KD;
            int kw = r2 - kh*KD;
            bv[t] = inb[ci*IND3 + kd*IND2 + kh*IND + kw];
        }
        __syncthreads();
        As[acol+0][arow] = a0.x; As[acol+1][arow] = a0.y;
        As[acol+2][arow] = a0.z; As[acol+3][arow] = a0.w;
        As[acol+4][arow] = a1.x; As[acol+5][arow] = a1.y;
        As[acol+6][arow] = a1.z; As[acol+7][arow] = a1.w;
        #pragma unroll
        for (int t = 0; t < 4; ++t) Bs[kkG+t][nnS] = bv[t];
        __syncthreads();
        #pragma unroll
        for (int kk = 0; kk < 16; ++kk) {
            float af[8], bf[4];
            *(float4*)&af[0] = *(const float4*)&As[kk][mIdx*8];
            *(float4*)&af[4] = *(const float4*)&As[kk][mIdx*8 + 4];
            *(float4*)&bf[0] = *(const float4*)&Bs[kk][nIdx*4];
            #pragma unroll
            for (int i = 0; i < 8; ++i)
                #pragma unroll
                for (int j = 0; j < 4; ++j)
                    acc[i][j] += af[i]*bf[j];
        }
    }

    const int sBase = s0 + nIdx*4;
    if constexpr (ATOMIC) {
        #pragma unroll
        for (int i = 0; i < 8; ++i) {
            int co = co0 + mIdx*8 + i;
            #pragma unroll
            for (int j = 0; j < 4; ++j)
                atomicAdd(&out[((size_t)b*cout + co)*OUT3 + sBase + j], acc[i][j]);
        }
    } else {
        #pragma unroll
        for (int i = 0; i < 8; ++i) {
            int co = co0 + mIdx*8 + i;
            float bb = bias[co];
            float4 v;
            v.x = acc[i][0] + bb; v.y = acc[i][1] + bb;
            v.z = acc[i][2] + bb; v.w = acc[i][3] + bb;
            if (RELU) {
                v.x = fmaxf(v.x, 0.f); v.y = fmaxf(v.y, 0.f);
                v.z = fmaxf(v.z, 0.f); v.w = fmaxf(v.w, 0.f);
            }
            *(float4*)&out[((size_t)b*cout + co)*OUT3 + sBase] = v;
        }
    }
}

// ---------------- squash primary capsules: p (B,256,64) -> u (B,2048,8) ----------------
__global__ __launch_bounds__(256)
void k_squash_u(const float* __restrict__ p_buf, const float* __restrict__ pbias,
                float* __restrict__ u)
{
    int g = blockIdx.x*256 + threadIdx.x;      // B*2048 = 4096
    int b = g >> 11;
    int i = g & 2047;
    int cap = i >> 6;
    int s   = i & 63;
    float vals[8];
    float sq = 0.f;
    #pragma unroll
    for (int c = 0; c < 8; ++c) {
        float x = p_buf[((size_t)(b*256) + cap*8 + c)*64 + s] + pbias[cap*8 + c];
        vals[c] = x;
        sq += x*x;
    }
    float scale = (sq / (1.f + sq)) / sqrtf(sq + 1e-8f);
    #pragma unroll
    for (int c = 0; c < 8; ++c) u[(size_t)g*8 + c] = vals[c]*scale;
}

// ---------------- routing (n_iter=1, softmax(0)=1/50): s[b,j,d]=(1/50)*sum_{i,c} W[j,i,d,c]u[b,i,c] ----------------
__global__ __launch_bounds__(256)
void k_route(const float* __restrict__ Wr, const float* __restrict__ u,
             float* __restrict__ s_buf)
{
    int j  = blockIdx.x;          // 50
    int i0 = blockIdx.y * 512;    // 4 splits
    __shared__ float us[2*512*8]; // 32 KB
    for (int idx = threadIdx.x; idx < 8192; idx += 256) {
        int b = idx >> 12;
        us[idx] = u[(size_t)b*16384 + (size_t)i0*8 + (idx & 4095)];
    }
    __syncthreads();
    int tid = threadIdx.x;
    int cc  = tid & 7;
    const float* Wj = Wr + (size_t)j*2048*512 + (size_t)i0*512;
    float a00 = 0.f, a01 = 0.f, a10 = 0.f, a11 = 0.f;
    for (int i = 0; i < 512; ++i) {
        float w0 = Wj[(size_t)i*512 + tid];
        float w1 = Wj[(size_t)i*512 + tid + 256];
        float u0 = us[i*8 + cc];
        float u1 = us[4096 + i*8 + cc];
        a00 += w0*u0; a01 += w1*u0; a10 += w0*u1; a11 += w1*u1;
    }
    __syncthreads();
    float* red = us;
    red[tid] = a00; red[256 + tid] = a01; red[512 + tid] = a10; red[768 + tid] = a11;
    __syncthreads();
    if (tid < 128) {
        int b = tid >> 6, d = tid & 63;
        const float* rb = red + b*512 + (d >> 5)*256 + (d & 31)*8;
        float s = 0.f;
        #pragma unroll
        for (int c2 = 0; c2 < 8; ++c2) s += rb[c2];
        atomicAdd(&s_buf[((size_t)b*50 + j)*64 + d], s * (1.0f/50.0f));
    }
}

// ---------------- squash v over d=64 ----------------
__global__ __launch_bounds__(64)
void k_squash_v(const float* __restrict__ s_buf, float* __restrict__ v_buf)
{
    int row = blockIdx.x;   // B*50 = 100
    int d   = threadIdx.x;  // 64
    float s  = s_buf[row*64 + d];
    float sq = s*s;
    #pragma unroll
    for (int o = 32; o > 0; o >>= 1) sq += __shfl_xor(sq, o);
    float scale = (sq / (1.f + sq)) / sqrtf(sq + 1e-8f);
    v_buf[row*64 + d] = s*scale;
}

// ---------------- dec1: ConvTranspose3d(50->128, k3, s3) — each out has exactly 1 tap ----------------
__global__ __launch_bounds__(256)
void k_dec1(const float* __restrict__ v, const float* __restrict__ W,
            const float* __restrict__ bias, float* __restrict__ d1)
{
    int g  = blockIdx.x*256 + threadIdx.x;  // B*128*1728 = 442368
    int o  = g % 1728;
    int co = (g / 1728) & 127;
    int b  = g / (1728*128);
    int ox = o / 144, oy = (o/12) % 12, oz = o % 12;
    int ix = ox/3, ka = ox - 3*ix;
    int iy = oy/3, kb = oy - 3*iy;
    int iz = oz/3, kc = oz - 3*iz;
    int widx = ka*9 + kb*3 + kc;
    int sidx = ix*16 + iy*4 + iz;
    float s = 0.f;
    for (int ci = 0; ci < 50; ++ci)
        s += v[((size_t)b*50 + ci)*64 + sidx] * W[((size_t)ci*128 + co)*27 + widx];
    d1[g] = fmaxf(s + bias[co], 0.f);
}

// ---------------- dec2: ConvTranspose3d(128->512, k3, s2, p1, op1) as zero-padded implicit GEMM ----------------
// d1: (B,128,12^3); W: (128,512,27); out NXC: (B, N3, 512)
__global__ __launch_bounds__(256)
void k_dec2(const float* __restrict__ d1, const float* __restrict__ W,
            const float* __restrict__ bias, float* __restrict__ out)
{
    constexpr int KTOT = 128*27;   // 3456
    constexpr int NCH  = KTOT/16;  // 216
    const int tid  = threadIdx.x;
    const int mIdx = tid >> 4;
    const int nIdx = tid & 15;
    const int n0g  = blockIdx.x * 64;   // over B*N3
    const int b    = n0g / N3;
    const int s0   = n0g % N3;
    const int co0  = blockIdx.y * 128;

    __shared__ float As[16][128];
    __shared__ float Bs[16][64];

    const int nnS = tid & 63;
    const int kkG = (tid >> 6) << 2;
    int sS = s0 + nnS;
    int ox = sS / 576, oy = (sS/24) % 24, oz = sS % 24;
    int oc3[3] = {ox, oy, oz};
    int  ixv[3][3];
    bool okv[3][3];
    #pragma unroll
    for (int d = 0; d < 3; ++d)
        #pragma unroll
        for (int kk = 0; kk < 3; ++kk) {
            int t = oc3[d] + 1 - kk;
            bool ok = (t >= 0) && ((t & 1) == 0) && (t < 24);
            okv[d][kk] = ok;
            ixv[d][kk] = ok ? (t >> 1) : 0;
        }
    const float* d1b = d1 + (size_t)b*128*1728;

    const int arow = tid >> 1;
    const int acol = (tid & 1)*8;

    float acc[8][4];
    #pragma unroll
    for (int i = 0; i < 8; ++i)
        #pragma unroll
        for (int j = 0; j < 4; ++j) acc[i][j] = 0.f;

    for (int c = 0; c < NCH; ++c) {
        int k0 = c*16;
        float av[8];
        #pragma unroll
        for (int t = 0; t < 8; ++t) {
            int k  = k0 + acol + t;
            int ci = k / 27;
            int kid = k - ci*27;
            av[t] = W[((size_t)ci*512 + co0 + arow)*27 + kid];
        }
        float bvv[4];
        #pragma unroll
        for (int t = 0; t < 4; ++t) {
            int k  = k0 + kkG + t;
            int ci = k / 27;
            int kid = k - ci*27;
            int kd = kid / 9;
            int r2 = kid - kd*9;
            int kh = r2 / 3;
            int kw = r2 - kh*3;
            bool ok = okv[0][kd] && okv[1][kh] && okv[2][kw];
            bvv[t] = ok ? d1b[ci*1728 + ixv[0][kd]*144 + ixv[1][kh]*12 + ixv[2][kw]] : 0.f;
        }
        __syncthreads();
        #pragma unroll
        for (int t = 0; t < 8; ++t) As[acol + t][arow] = av[t];
        #pragma unroll
        for (int t = 0; t < 4; ++t) Bs[kkG + t][nnS] = bvv[t];
        __syncthreads();
        #pragma unroll
        for (int kk = 0; kk < 16; ++kk) {
            float af[8], bf[4];
            *(float4*)&af[0] = *(const float4*)&As[kk][mIdx*8];
            *(float4*)&af[4] = *(const float4*)&As[kk][mIdx*8 + 4];
            *(float4*)&bf[0] = *(const float4*)&Bs[kk][nIdx*4];
            #pragma unroll
            for (int i = 0; i < 8; ++i)
                #pragma unroll
                for (int j = 0; j < 4; ++j)
                    acc[i][j] += af[i]*bf[j];
        }
    }

    float bb[8];
    #pragma unroll
    for (int i = 0; i < 8; ++i) bb[i] = bias[co0 + mIdx*8 + i];
    #pragma unroll
    for (int j = 0; j < 4; ++j) {
        int o = s0 + nIdx*4 + j;
        float* dst = out + ((size_t)b*N3 + o)*512 + co0 + mIdx*8;
        float4 v0, v1;
        v0.x = fmaxf(acc[0][j] + bb[0], 0.f);
        v0.y = fmaxf(acc[1][j] + bb[1], 0.f);
        v0.z = fmaxf(acc[2][j] + bb[2], 0.f);
        v0.w = fmaxf(acc[3][j] + bb[3], 0.f);
        v1.x = fmaxf(acc[4][j] + bb[4], 0.f);
        v1.y = fmaxf(acc[5][j] + bb[5], 0.f);
        v1.z = fmaxf(acc[6][j] + bb[6], 0.f);
        v1.w = fmaxf(acc[7][j] + bb[7], 0.f);
        *(float4*)dst       = v0;
        *(float4*)(dst + 4) = v1;
    }
}

// ---------------- final gather: out[b,p,:] = d2t[b, vid[b,p], :] ----------------
__global__ __launch_bounds__(256)
void k_gather(const float* __restrict__ d2t, const int* __restrict__ vid,
              float* __restrict__ out)
{
    int g  = blockIdx.x*256 + threadIdx.x;   // B*P*128 float4 units
    int q  = g & 127;
    int bp = g >> 7;
    int v  = vid[bp];
    int b  = bp >> 13;
    float4 val = *(const float4*)&d2t[((size_t)b*N3 + v)*512 + q*4];
    *(float4*)&out[(size_t)bp*512 + q*4] = val;
}

extern "C" void kernel_launch(void* const* d_in, const int* in_sizes, int n_in,
                              void* d_out, int out_size, void* d_ws, size_t ws_size,
                              hipStream_t stream)
{
    (void)in_sizes; (void)n_in; (void)out_size; (void)ws_size;
    const float* pcl  = (const float*)d_in[0];
    const float* feat = (const float*)d_in[1];
    const float* c1w  = (const float*)d_in[3];
    const float* c1b  = (const float*)d_in[4];
    const float* c2w  = (const float*)d_in[5];
    const float* c2b  = (const float*)d_in[6];
    const float* pw   = (const float*)d_in[7];
    const float* pb   = (const float*)d_in[8];
    const float* rw   = (const float*)d_in[9];
    const float* d1w  = (const float*)d_in[10];
    const float* d1b_ = (const float*)d_in[11];
    const float* d2w  = (const float*)d_in[12];
    const float* d2b  = (const float*)d_in[13];

    char* ws = (char*)d_ws;
    // d2t occupies [0, 56,623,104) and aliases the (dead-by-then) mesh/h1/h2 buffers.
    float* d2t   = (float*)ws;
    float* meshS = (float*)ws;                      // 14,155,776 B
    float* meshT = (float*)(ws + 14155776);         // 14,155,776 B
    float* h1    = (float*)(ws + 28311552);         // 16,384,000 B
    float* h2    = (float*)(ws + 44695552);         //  8,388,608 B (ends 53,084,160)
    char* tail = ws + 56623104;
    int*   vid   = (int*)tail;        tail += 65536;
    float* p_buf = (float*)tail;      tail += 131072;
    float* u_buf = (float*)tail;      tail += 131072;
    float* s_buf = (float*)tail;      tail += 25600;
    float* v_buf = (float*)tail;      tail += 25600;
    float* d1    = (float*)tail;      tail += 1769472;

    k_vid<<<dim3(B_), dim3(256), 0, stream>>>(pcl, vid);

    hipMemsetAsync(meshS, 0, 14155776, stream);
    k_scatter<<<dim3(8192), dim3(256), 0, stream>>>(feat, vid, meshS);
    k_transpose<<<dim3(432, 4, 2), dim3(256), 0, stream>>>(meshS, meshT);

    // conv1: 128->256, k5, 24^3 -> 20^3
    k_conv<128,5,1,24,20,true,false><<<dim3(250, 2, 1), dim3(256), 0, stream>>>(
        meshT, c1w, c1b, h1, 256);
    // conv2: 256->256, k5, 20^3 -> 16^3
    k_conv<256,5,1,20,16,true,false><<<dim3(128, 2, 1), dim3(256), 0, stream>>>(
        h1, c2w, c2b, h2, 256);
    // primary caps: 256->256, k9, s2, 16^3 -> 4^3, split-K atomic accumulate
    hipMemsetAsync(p_buf, 0, 131072, stream);
    k_conv<256,9,2,16,4,false,true><<<dim3(2, 2, 128), dim3(256), 0, stream>>>(
        h2, pw, nullptr, p_buf, 256);

    k_squash_u<<<dim3(16), dim3(256), 0, stream>>>(p_buf, pb, u_buf);

    hipMemsetAsync(s_buf, 0, 25600, stream);
    k_route<<<dim3(50, 4), dim3(256), 0, stream>>>(rw, u_buf, s_buf);
    k_squash_v<<<dim3(100), dim3(64), 0, stream>>>(s_buf, v_buf);

    k_dec1<<<dim3(1728), dim3(256), 0, stream>>>(v_buf, d1w, d1b_, d1);
    k_dec2<<<dim3(432, 4), dim3(256), 0, stream>>>(d1, d2w, d2b, d2t);

    k_gather<<<dim3(8192), dim3(256), 0, stream>>>(d2t, vid, (float*)d_out);
}

// Round 2
// 8643.967 us; speedup vs baseline: 1.1335x; 1.1335x over previous
//
#include <hip/hip_runtime.h>
#include <cstdint>
#include <cstddef>

#define B_   2
#define P_   8192
#define C_   128
#define NVOX 24
#define N3   (NVOX*NVOX*NVOX)   // 13824

// ---------------- voxel ids ----------------
__global__ __launch_bounds__(256)
void k_vid(const float* __restrict__ pcl, int* __restrict__ vid)
{
    int b = blockIdx.x;
    const float* pb = pcl + (size_t)b * P_ * 3;
    float mn[3] = {3e38f, 3e38f, 3e38f};
    float mx[3] = {-3e38f, -3e38f, -3e38f};
    for (int p = threadIdx.x; p < P_; p += 256) {
        #pragma unroll
        for (int d = 0; d < 3; ++d) {
            float v = pb[p*3 + d];
            mn[d] = fminf(mn[d], v);
            mx[d] = fmaxf(mx[d], v);
        }
    }
    __shared__ float red[6][256];
    #pragma unroll
    for (int d = 0; d < 3; ++d) { red[d][threadIdx.x] = mn[d]; red[3+d][threadIdx.x] = mx[d]; }
    __syncthreads();
    for (int s = 128; s > 0; s >>= 1) {
        if (threadIdx.x < (unsigned)s) {
            #pragma unroll
            for (int d = 0; d < 3; ++d) {
                red[d][threadIdx.x]   = fminf(red[d][threadIdx.x],   red[d][threadIdx.x + s]);
                red[3+d][threadIdx.x] = fmaxf(red[3+d][threadIdx.x], red[3+d][threadIdx.x + s]);
            }
        }
        __syncthreads();
    }
    float mn0 = red[0][0], mn1 = red[1][0], mn2 = red[2][0];
    float dd0 = red[3][0] - mn0 + 1e-9f;
    float dd1 = red[4][0] - mn1 + 1e-9f;
    float dd2 = red[5][0] - mn2 + 1e-9f;
    for (int p = threadIdx.x; p < P_; p += 256) {
        float fx = (pb[p*3+0] - mn0) / dd0 * 24.0f;
        float fy = (pb[p*3+1] - mn1) / dd1 * 24.0f;
        float fz = (pb[p*3+2] - mn2) / dd2 * 24.0f;
        int ix = (int)floorf(fx); ix = ix < 0 ? 0 : (ix > 23 ? 23 : ix);
        int iy = (int)floorf(fy); iy = iy < 0 ? 0 : (iy > 23 ? 23 : iy);
        int iz = (int)floorf(fz); iz = iz < 0 ? 0 : (iz > 23 ? 23 : iz);
        vid[b*P_ + p] = ix*576 + iy*24 + iz;
    }
}

// ---------------- scatter-add point features -> (B, N3, C) ----------------
__global__ __launch_bounds__(256)
void k_scatter(const float* __restrict__ feat, const int* __restrict__ vid,
               float* __restrict__ meshS)
{
    int g = blockIdx.x*256 + threadIdx.x;      // B*P*C = 2,097,152
    int c  = g & (C_-1);
    int bp = g >> 7;
    int v  = vid[bp];
    int b  = bp >> 13;                          // P = 2^13
    atomicAdd(&meshS[((size_t)b*N3 + v)*C_ + c], feat[g]);
}

// ---------------- transpose (B,N3,C) -> (B,C,N3) ----------------
__global__ __launch_bounds__(256)
void k_transpose(const float* __restrict__ meshS, float* __restrict__ meshT)
{
    __shared__ float tile[32][33];
    int b  = blockIdx.z;
    int v0 = blockIdx.x * 32;   // 432 tiles
    int c0 = blockIdx.y * 32;   // 4 tiles
    int i = threadIdx.x >> 5;   // 0..7
    int j = threadIdx.x & 31;
    #pragma unroll
    for (int r = 0; r < 32; r += 8)
        tile[i+r][j] = meshS[((size_t)b*N3 + v0 + i + r)*C_ + c0 + j];
    __syncthreads();
    #pragma unroll
    for (int r = 0; r < 32; r += 8)
        meshT[((size_t)b*C_ + c0 + i + r)*N3 + v0 + j] = tile[j][i+r];
}

// ---------------- 128x128x16 implicit-GEMM conv, split-K atomic ----------------
// in: (B, CIN, IND^3); W: (256, CIN*KD^3); out: (B, 256, OUT3) accumulated with atomics.
// 256 threads, 8x8 per-thread tile. grid = (B*OUT3/128, 2, splitk)
template<int CIN, int KD, int STRIDE, int IND, int OUTD>
__global__ __launch_bounds__(256, 4)
void k_gemm_conv(const float* __restrict__ in, const float* __restrict__ W,
                 float* __restrict__ out)
{
    constexpr int KD2  = KD*KD;
    constexpr int K3   = KD*KD*KD;
    constexpr int IND2 = IND*IND;
    constexpr int IND3 = IND2*IND;
    constexpr int OUT2 = OUTD*OUTD;
    constexpr int OUT3 = OUT2*OUTD;
    constexpr int KTOT = CIN*K3;
    constexpr int NCH  = KTOT/16;

    const int tid  = threadIdx.x;
    const int mIdx = tid >> 4;
    const int nIdx = tid & 15;
    const int n0   = blockIdx.x * 128;
    const int co0  = blockIdx.y * 128;
    const int per  = NCH / (int)gridDim.z;
    const int c0   = blockIdx.z * per;
    const int c1   = c0 + per;

    __shared__ float As[16][132];   // pad 4: stores & reads <=2-way
    __shared__ float Bs[16][128];

    // B staging: one n per thread, 8 k-rows (p*2 + kHalf)
    const int nB    = n0 + (tid & 127);
    const int kHalf = tid >> 7;
    int bB = nB / OUT3;
    int sB = nB - bB*OUT3;
    int xB = sB / OUT2;
    int yB = (sB / OUTD) % OUTD;
    int zB = sB % OUTD;
    const float* inB = in + (size_t)bB*CIN*IND3
                          + (xB*STRIDE)*IND2 + (yB*STRIDE)*IND + (zB*STRIDE);

    // A staging: two float4 rows per thread
    const int aCo = tid >> 2;          // 0..63
    const int aKq = (tid & 3) * 4;     // 0,4,8,12
    const float* Wr0 = W + (size_t)(co0 + aCo)*KTOT + aKq;
    const float* Wr1 = W + (size_t)(co0 + 64 + aCo)*KTOT + aKq;

    float acc[8][8];
    #pragma unroll
    for (int i = 0; i < 8; ++i)
        #pragma unroll
        for (int j = 0; j < 8; ++j) acc[i][j] = 0.f;

    for (int c = c0; c < c1; ++c) {
        const int kb = c*16;
        float4 a0 = *(const float4*)(Wr0 + kb);
        float4 a1 = *(const float4*)(Wr1 + kb);
        float bv[8];
        #pragma unroll
        for (int p = 0; p < 8; ++p) {
            int k  = kb + p*2 + kHalf;
            int ci = k / K3;
            int r  = k - ci*K3;
            int kd = r / KD2;
            int r2 = r - kd*KD2;
            int kh = r2 / KD;
            int kw = r2 - kh*KD;
            bv[p] = inB[ci*IND3 + kd*IND2 + kh*IND + kw];
        }
        __syncthreads();
        As[aKq+0][aCo] = a0.x; As[aKq+1][aCo] = a0.y;
        As[aKq+2][aCo] = a0.z; As[aKq+3][aCo] = a0.w;
        As[aKq+0][64+aCo] = a1.x; As[aKq+1][64+aCo] = a1.y;
        As[aKq+2][64+aCo] = a1.z; As[aKq+3][64+aCo] = a1.w;
        #pragma unroll
        for (int p = 0; p < 8; ++p) Bs[p*2 + kHalf][tid & 127] = bv[p];
        __syncthreads();
        #pragma unroll
        for (int kk = 0; kk < 16; ++kk) {
            float af[8], bf[8];
            *(float4*)&af[0] = *(const float4*)&As[kk][mIdx*8];
            *(float4*)&af[4] = *(const float4*)&As[kk][mIdx*8 + 4];
            *(float4*)&bf[0] = *(const float4*)&Bs[kk][nIdx*8];
            *(float4*)&bf[4] = *(const float4*)&Bs[kk][nIdx*8 + 4];
            #pragma unroll
            for (int i = 0; i < 8; ++i)
                #pragma unroll
                for (int j = 0; j < 8; ++j)
                    acc[i][j] += af[i]*bf[j];
        }
    }

    #pragma unroll
    for (int j = 0; j < 8; ++j) {
        int n = n0 + nIdx*8 + j;
        int b = n / OUT3;
        int s = n - b*OUT3;
        float* o = out + ((size_t)b*256 + co0 + mIdx*8)*OUT3 + s;
        #pragma unroll
        for (int i = 0; i < 8; ++i)
            atomicAdd(o + (size_t)i*OUT3, acc[i][j]);
    }
}

// ---------------- bias + relu epilogue (after split-K accumulation) ----------------
template<int OUT3>
__global__ __launch_bounds__(256)
void k_biasrelu(float* __restrict__ buf, const float* __restrict__ bias, int total)
{
    int g = blockIdx.x*256 + threadIdx.x;
    if (g >= total) return;
    int co = (g / OUT3) & 255;
    buf[g] = fmaxf(buf[g] + bias[co], 0.f);
}

// ---------------- squash primary capsules: p (B,256,64) -> u (B,2048,8) ----------------
__global__ __launch_bounds__(256)
void k_squash_u(const float* __restrict__ p_buf, const float* __restrict__ pbias,
                float* __restrict__ u)
{
    int g = blockIdx.x*256 + threadIdx.x;      // B*2048 = 4096
    int b = g >> 11;
    int i = g & 2047;
    int cap = i >> 6;
    int s   = i & 63;
    float vals[8];
    float sq = 0.f;
    #pragma unroll
    for (int c = 0; c < 8; ++c) {
        float x = p_buf[((size_t)(b*256) + cap*8 + c)*64 + s] + pbias[cap*8 + c];
        vals[c] = x;
        sq += x*x;
    }
    float scale = (sq / (1.f + sq)) / sqrtf(sq + 1e-8f);
    #pragma unroll
    for (int c = 0; c < 8; ++c) u[(size_t)g*8 + c] = vals[c]*scale;
}

// ---------------- routing (n_iter=1): s[b,j,d]=(1/50)*sum_{i,c} W[j,i,d,c]u[b,i,c] ----------------
__global__ __launch_bounds__(256)
void k_route(const float* __restrict__ Wr, const float* __restrict__ u,
             float* __restrict__ s_buf)
{
    int j  = blockIdx.x;          // 50
    int i0 = blockIdx.y * 512;    // 4 splits
    __shared__ float us[2*512*8]; // 32 KB
    for (int idx = threadIdx.x; idx < 8192; idx += 256) {
        int b = idx >> 12;
        us[idx] = u[(size_t)b*16384 + (size_t)i0*8 + (idx & 4095)];
    }
    __syncthreads();
    int tid = threadIdx.x;
    int cc  = tid & 7;
    const float* Wj = Wr + (size_t)j*2048*512 + (size_t)i0*512;
    float a00 = 0.f, a01 = 0.f, a10 = 0.f, a11 = 0.f;
    for (int i = 0; i < 512; ++i) {
        float w0 = Wj[(size_t)i*512 + tid];
        float w1 = Wj[(size_t)i*512 + tid + 256];
        float u0 = us[i*8 + cc];
        float u1 = us[4096 + i*8 + cc];
        a00 += w0*u0; a01 += w1*u0; a10 += w0*u1; a11 += w1*u1;
    }
    __syncthreads();
    float* red = us;
    red[tid] = a00; red[256 + tid] = a01; red[512 + tid] = a10; red[768 + tid] = a11;
    __syncthreads();
    if (tid < 128) {
        int b = tid >> 6, d = tid & 63;
        const float* rb = red + b*512 + (d >> 5)*256 + (d & 31)*8;
        float s = 0.f;
        #pragma unroll
        for (int c2 = 0; c2 < 8; ++c2) s += rb[c2];
        atomicAdd(&s_buf[((size_t)b*50 + j)*64 + d], s * (1.0f/50.0f));
    }
}

// ---------------- squash v over d=64 ----------------
__global__ __launch_bounds__(64)
void k_squash_v(const float* __restrict__ s_buf, float* __restrict__ v_buf)
{
    int row = blockIdx.x;   // B*50 = 100
    int d   = threadIdx.x;  // 64
    float s  = s_buf[row*64 + d];
    float sq = s*s;
    #pragma unroll
    for (int o = 32; o > 0; o >>= 1) sq += __shfl_xor(sq, o);
    float scale = (sq / (1.f + sq)) / sqrtf(sq + 1e-8f);
    v_buf[row*64 + d] = s*scale;
}

// ---------------- dec1: ConvTranspose3d(50->128, k3, s3) — exactly 1 tap per output ----------------
__global__ __launch_bounds__(256)
void k_dec1(const float* __restrict__ v, const float* __restrict__ W,
            const float* __restrict__ bias, float* __restrict__ d1)
{
    int g  = blockIdx.x*256 + threadIdx.x;  // B*128*1728 = 442368
    int o  = g % 1728;
    int co = (g / 1728) & 127;
    int b  = g / (1728*128);
    int ox = o / 144, oy = (o/12) % 12, oz = o % 12;
    int ix = ox/3, ka = ox - 3*ix;
    int iy = oy/3, kb = oy - 3*iy;
    int iz = oz/3, kc = oz - 3*iz;
    int widx = ka*9 + kb*3 + kc;
    int sidx = ix*16 + iy*4 + iz;
    float s = 0.f;
    for (int ci = 0; ci < 50; ++ci)
        s += v[((size_t)b*50 + ci)*64 + sidx] * W[((size_t)ci*128 + co)*27 + widx];
    d1[g] = fmaxf(s + bias[co], 0.f);
}

// ---------------- dec2: ConvTranspose3d(128->512, k3, s2, p1, op1), 128x128 GEMM ----------------
// d1: (B,128,12^3); W: (128,512,27); out: (B, N3, 512)  [NXC for coalesced gather]
__global__ __launch_bounds__(256, 4)
void k_dec2g(const float* __restrict__ d1, const float* __restrict__ W,
             const float* __restrict__ bias, float* __restrict__ out)
{
    const int tid  = threadIdx.x;
    const int mIdx = tid >> 4;
    const int nIdx = tid & 15;
    const int n0   = blockIdx.x * 128;   // over B*N3 = 27648
    const int co0  = blockIdx.y * 128;   // over 512

    __shared__ float As[16][132];
    __shared__ float Bs[16][128];

    const int nB    = n0 + (tid & 127);
    const int kHalf = tid >> 7;
    int b  = nB / N3;
    int s  = nB - b*N3;
    int ox = s / 576, oy = (s/24) % 24, oz = s % 24;
    const float* d1b = d1 + (size_t)b*128*1728;

    float acc[8][8];
    #pragma unroll
    for (int i = 0; i < 8; ++i)
        #pragma unroll
        for (int j = 0; j < 8; ++j) acc[i][j] = 0.f;

    for (int c = 0; c < 216; ++c) {   // NCH = 128*27/16
        const int kb = c*16;
        // A: 8 scalar tasks — co = p*16 + (tid>>4), kk = tid&15
        float av[8];
        #pragma unroll
        for (int p = 0; p < 8; ++p) {
            int kkA = tid & 15;
            int coA = p*16 + (tid >> 4);
            int k   = kb + kkA;
            int ci  = k / 27;
            int kid = k - ci*27;
            av[p] = W[((size_t)ci*512 + co0 + coA)*27 + kid];
        }
        // B: 8 scalar tasks — parity-gated transposed-conv tap
        float bv[8];
        #pragma unroll
        for (int p = 0; p < 8; ++p) {
            int k   = kb + p*2 + kHalf;
            int ci  = k / 27;
            int kid = k - ci*27;
            int kd  = kid / 9;
            int r2  = kid - kd*9;
            int kh  = r2 / 3;
            int kw  = r2 - kh*3;
            int tx = ox + 1 - kd;
            int ty = oy + 1 - kh;
            int tz = oz + 1 - kw;
            bool ok = (((tx | ty | tz) & 1) == 0) &&
                      ((unsigned)tx < 24u) && ((unsigned)ty < 24u) && ((unsigned)tz < 24u);
            bv[p] = ok ? d1b[ci*1728 + (tx>>1)*144 + (ty>>1)*12 + (tz>>1)] : 0.f;
        }
        __syncthreads();
        #pragma unroll
        for (int p = 0; p < 8; ++p) As[tid & 15][p*16 + (tid >> 4)] = av[p];
        #pragma unroll
        for (int p = 0; p < 8; ++p) Bs[p*2 + kHalf][tid & 127] = bv[p];
        __syncthreads();
        #pragma unroll
        for (int kk = 0; kk < 16; ++kk) {
            float af[8], bf[8];
            *(float4*)&af[0] = *(const float4*)&As[kk][mIdx*8];
            *(float4*)&af[4] = *(const float4*)&As[kk][mIdx*8 + 4];
            *(float4*)&bf[0] = *(const float4*)&Bs[kk][nIdx*8];
            *(float4*)&bf[4] = *(const float4*)&Bs[kk][nIdx*8 + 4];
            #pragma unroll
            for (int i = 0; i < 8; ++i)
                #pragma unroll
                for (int j = 0; j < 8; ++j)
                    acc[i][j] += af[i]*bf[j];
        }
    }

    float bb[8];
    #pragma unroll
    for (int i = 0; i < 8; ++i) bb[i] = bias[co0 + mIdx*8 + i];
    #pragma unroll
    for (int j = 0; j < 8; ++j) {
        int n = n0 + nIdx*8 + j;
        float* dst = out + (size_t)n*512 + co0 + mIdx*8;
        float4 v0, v1;
        v0.x = fmaxf(acc[0][j] + bb[0], 0.f);
        v0.y = fmaxf(acc[1][j] + bb[1], 0.f);
        v0.z = fmaxf(acc[2][j] + bb[2], 0.f);
        v0.w = fmaxf(acc[3][j] + bb[3], 0.f);
        v1.x = fmaxf(acc[4][j] + bb[4], 0.f);
        v1.y = fmaxf(acc[5][j] + bb[5], 0.f);
        v1.z = fmaxf(acc[6][j] + bb[6], 0.f);
        v1.w = fmaxf(acc[7][j] + bb[7], 0.f);
        *(float4*)dst       = v0;
        *(float4*)(dst + 4) = v1;
    }
}

// ---------------- final gather: out[b,p,:] = d2t[b, vid[b,p], :] ----------------
__global__ __launch_bounds__(256)
void k_gather(const float* __restrict__ d2t, const int* __restrict__ vid,
              float* __restrict__ out)
{
    int g  = blockIdx.x*256 + threadIdx.x;   // B*P*128 float4 units
    int q  = g & 127;
    int bp = g >> 7;
    int v  = vid[bp];
    int b  = bp >> 13;
    float4 val = *(const float4*)&d2t[((size_t)b*N3 + v)*512 + q*4];
    *(float4*)&out[(size_t)bp*512 + q*4] = val;
}

extern "C" void kernel_launch(void* const* d_in, const int* in_sizes, int n_in,
                              void* d_out, int out_size, void* d_ws, size_t ws_size,
                              hipStream_t stream)
{
    (void)in_sizes; (void)n_in; (void)out_size; (void)ws_size;
    const float* pcl  = (const float*)d_in[0];
    const float* feat = (const float*)d_in[1];
    const float* c1w  = (const float*)d_in[3];
    const float* c1b  = (const float*)d_in[4];
    const float* c2w  = (const float*)d_in[5];
    const float* c2b  = (const float*)d_in[6];
    const float* pw   = (const float*)d_in[7];
    const float* pb   = (const float*)d_in[8];
    const float* rw   = (const float*)d_in[9];
    const float* d1w  = (const float*)d_in[10];
    const float* d1b_ = (const float*)d_in[11];
    const float* d2w  = (const float*)d_in[12];
    const float* d2b  = (const float*)d_in[13];

    char* ws = (char*)d_ws;
    // d2t occupies [0, 56,623,104) and aliases the (dead-by-then) mesh/h1/h2 buffers.
    float* d2t   = (float*)ws;
    float* meshS = (float*)ws;                      // 14,155,776 B
    float* meshT = (float*)(ws + 14155776);         // 14,155,776 B
    float* h1    = (float*)(ws + 28311552);         // 16,384,000 B
    float* h2    = (float*)(ws + 44695552);         //  8,388,608 B (ends 53,084,160)
    char* tail = ws + 56623104;
    int*   vid   = (int*)tail;        tail += 65536;
    float* p_buf = (float*)tail;      tail += 131072;
    float* u_buf = (float*)tail;      tail += 131072;
    float* s_buf = (float*)tail;      tail += 25600;
    float* v_buf = (float*)tail;      tail += 25600;
    float* d1    = (float*)tail;      tail += 1769472;

    k_vid<<<dim3(B_), dim3(256), 0, stream>>>(pcl, vid);

    hipMemsetAsync(meshS, 0, 14155776, stream);
    k_scatter<<<dim3(8192), dim3(256), 0, stream>>>(feat, vid, meshS);
    k_transpose<<<dim3(432, 4, 2), dim3(256), 0, stream>>>(meshS, meshT);

    // conv1: 128->256, k5, 24^3 -> 20^3. N = 2*8000 = 16000 -> 125 tiles; splitk 8.
    hipMemsetAsync(h1, 0, 16384000, stream);
    k_gemm_conv<128,5,1,24,20><<<dim3(125, 2, 8), dim3(256), 0, stream>>>(meshT, c1w, h1);
    k_biasrelu<8000><<<dim3(16000), dim3(256), 0, stream>>>(h1, c1b, 4096000);

    // conv2: 256->256, k5, 20^3 -> 16^3. N = 2*4096 = 8192 -> 64 tiles; splitk 8.
    hipMemsetAsync(h2, 0, 8388608, stream);
    k_gemm_conv<256,5,1,20,16><<<dim3(64, 2, 8), dim3(256), 0, stream>>>(h1, c2w, h2);
    k_biasrelu<4096><<<dim3(8192), dim3(256), 0, stream>>>(h2, c2b, 2097152);

    // primary caps: 256->256, k9, s2, 16^3 -> 4^3. N = 128 -> 1 tile; splitk 108.
    hipMemsetAsync(p_buf, 0, 131072, stream);
    k_gemm_conv<256,9,2,16,4><<<dim3(1, 2, 108), dim3(256), 0, stream>>>(h2, pw, p_buf);

    k_squash_u<<<dim3(16), dim3(256), 0, stream>>>(p_buf, pb, u_buf);

    hipMemsetAsync(s_buf, 0, 25600, stream);
    k_route<<<dim3(50, 4), dim3(256), 0, stream>>>(rw, u_buf, s_buf);
    k_squash_v<<<dim3(100), dim3(64), 0, stream>>>(s_buf, v_buf);

    k_dec1<<<dim3(1728), dim3(256), 0, stream>>>(v_buf, d1w, d1b_, d1);
    k_dec2g<<<dim3(216, 4), dim3(256), 0, stream>>>(d1, d2w, d2b, d2t);

    k_gather<<<dim3(8192), dim3(256), 0, stream>>>(d2t, vid, (float*)d_out);
}

// Round 3
// 5695.727 us; speedup vs baseline: 1.7202x; 1.5176x over previous
//
#include <hip/hip_runtime.h>
#include <cstdint>
#include <cstddef>

#define B_   2
#define P_   8192
#define C_   128
#define NVOX 24
#define N3   (NVOX*NVOX*NVOX)   // 13824

// ---------------- voxel ids ----------------
__global__ __launch_bounds__(256)
void k_vid(const float* __restrict__ pcl, int* __restrict__ vid)
{
    int b = blockIdx.x;
    const float* pb = pcl + (size_t)b * P_ * 3;
    float mn[3] = {3e38f, 3e38f, 3e38f};
    float mx[3] = {-3e38f, -3e38f, -3e38f};
    for (int p = threadIdx.x; p < P_; p += 256) {
        #pragma unroll
        for (int d = 0; d < 3; ++d) {
            float v = pb[p*3 + d];
            mn[d] = fminf(mn[d], v);
            mx[d] = fmaxf(mx[d], v);
        }
    }
    __shared__ float red[6][256];
    #pragma unroll
    for (int d = 0; d < 3; ++d) { red[d][threadIdx.x] = mn[d]; red[3+d][threadIdx.x] = mx[d]; }
    __syncthreads();
    for (int s = 128; s > 0; s >>= 1) {
        if (threadIdx.x < (unsigned)s) {
            #pragma unroll
            for (int d = 0; d < 3; ++d) {
                red[d][threadIdx.x]   = fminf(red[d][threadIdx.x],   red[d][threadIdx.x + s]);
                red[3+d][threadIdx.x] = fmaxf(red[3+d][threadIdx.x], red[3+d][threadIdx.x + s]);
            }
        }
        __syncthreads();
    }
    float mn0 = red[0][0], mn1 = red[1][0], mn2 = red[2][0];
    float dd0 = red[3][0] - mn0 + 1e-9f;
    float dd1 = red[4][0] - mn1 + 1e-9f;
    float dd2 = red[5][0] - mn2 + 1e-9f;
    for (int p = threadIdx.x; p < P_; p += 256) {
        float fx = (pb[p*3+0] - mn0) / dd0 * 24.0f;
        float fy = (pb[p*3+1] - mn1) / dd1 * 24.0f;
        float fz = (pb[p*3+2] - mn2) / dd2 * 24.0f;
        int ix = (int)floorf(fx); ix = ix < 0 ? 0 : (ix > 23 ? 23 : ix);
        int iy = (int)floorf(fy); iy = iy < 0 ? 0 : (iy > 23 ? 23 : iy);
        int iz = (int)floorf(fz); iz = iz < 0 ? 0 : (iz > 23 ? 23 : iz);
        vid[b*P_ + p] = ix*576 + iy*24 + iz;
    }
}

// ---------------- scatter-add point features -> (B, N3, C) ----------------
__global__ __launch_bounds__(256)
void k_scatter(const float* __restrict__ feat, const int* __restrict__ vid,
               float* __restrict__ meshS)
{
    int g = blockIdx.x*256 + threadIdx.x;      // B*P*C = 2,097,152
    int c  = g & (C_-1);
    int bp = g >> 7;
    int v  = vid[bp];
    int b  = bp >> 13;
    atomicAdd(&meshS[((size_t)b*N3 + v)*C_ + c], feat[g]);
}

// ---------------- transpose (B,N3,C) -> (B,C,N3) ----------------
__global__ __launch_bounds__(256)
void k_transpose(const float* __restrict__ meshS, float* __restrict__ meshT)
{
    __shared__ float tile[32][33];
    int b  = blockIdx.z;
    int v0 = blockIdx.x * 32;
    int c0 = blockIdx.y * 32;
    int i = threadIdx.x >> 5;
    int j = threadIdx.x & 31;
    #pragma unroll
    for (int r = 0; r < 32; r += 8)
        tile[i+r][j] = meshS[((size_t)b*N3 + v0 + i + r)*C_ + c0 + j];
    __syncthreads();
    #pragma unroll
    for (int r = 0; r < 32; r += 8)
        meshT[((size_t)b*C_ + c0 + i + r)*N3 + v0 + j] = tile[j][i+r];
}

// LDS layout note: an 8-float column block c=8t+u is stored split: u=0..3 at
// word t*4+u, u=4..7 at word 64+t*4+(u-4). All staging writes and inner reads
// are then <=2-way bank aliased (free). Rows padded to 132 words.

// ---------------- 128x128x16 implicit-GEMM conv, split-K atomic ----------------
template<int CIN, int KD, int STRIDE, int IND, int OUTD>
__global__ __launch_bounds__(256, 2)
void k_gemm_conv(const float* __restrict__ in, const float* __restrict__ W,
                 float* __restrict__ out)
{
    constexpr int KD2  = KD*KD;
    constexpr int K3   = KD*KD*KD;
    constexpr int IND2 = IND*IND;
    constexpr int IND3 = IND2*IND;
    constexpr int OUT2 = OUTD*OUTD;
    constexpr int OUT3 = OUT2*OUTD;
    constexpr int KTOT = CIN*K3;
    constexpr int NCH  = KTOT/16;

    const int tid  = threadIdx.x;
    const int mIdx = tid >> 4;
    const int nIdx = tid & 15;
    const int n0   = blockIdx.x * 128;
    const int co0  = blockIdx.y * 128;
    const int per  = NCH / (int)gridDim.z;
    const int c0   = blockIdx.z * per;
    const int c1   = c0 + per;

    __shared__ float As[16][132];
    __shared__ float Bs[16][132];

    // B staging: one n per thread, 8 k-rows (p*2 + kHalf)
    const int nB    = n0 + (tid & 127);
    const int kHalf = tid >> 7;
    int bB = nB / OUT3;
    int sB = nB - bB*OUT3;
    int xB = sB / OUT2;
    int yB = (sB / OUTD) % OUTD;
    int zB = sB % OUTD;
    const float* inB = in + (size_t)bB*CIN*IND3
                          + (xB*STRIDE)*IND2 + (yB*STRIDE)*IND + (zB*STRIDE);
    const int cB  = tid & 127;
    const int qB  = cB >> 2;
    const int bpos = ((((qB & 1) << 4) | (qB >> 1)) << 2) | (cB & 3);

    // A staging: two float4 (k-dim) per thread
    const int aCo = tid >> 2;          // 0..63
    const int aKq = (tid & 3) * 4;     // 0,4,8,12
    const int qA  = aCo >> 2;
    const int apos = ((((qA & 1) << 4) | (qA >> 1)) << 2) | (aCo & 3);
    const float* Wr0 = W + (size_t)(co0 + aCo)*KTOT + aKq;
    const float* Wr1 = W + (size_t)(co0 + 64 + aCo)*KTOT + aKq;

    float acc[8][8];
    #pragma unroll
    for (int i = 0; i < 8; ++i)
        #pragma unroll
        for (int j = 0; j < 8; ++j) acc[i][j] = 0.f;

    for (int c = c0; c < c1; ++c) {
        const int kb = c*16;
        float4 a0 = *(const float4*)(Wr0 + kb);
        float4 a1 = *(const float4*)(Wr1 + kb);
        float bv[8];
        #pragma unroll
        for (int p = 0; p < 8; ++p) {
            int k  = kb + p*2 + kHalf;
            int ci = k / K3;
            int r  = k - ci*K3;
            int kd = r / KD2;
            int r2 = r - kd*KD2;
            int kh = r2 / KD;
            int kw = r2 - kh*KD;
            bv[p] = inB[ci*IND3 + kd*IND2 + kh*IND + kw];
        }
        __syncthreads();
        As[aKq+0][apos] = a0.x; As[aKq+1][apos] = a0.y;
        As[aKq+2][apos] = a0.z; As[aKq+3][apos] = a0.w;
        As[aKq+0][apos+32] = a1.x; As[aKq+1][apos+32] = a1.y;
        As[aKq+2][apos+32] = a1.z; As[aKq+3][apos+32] = a1.w;
        #pragma unroll
        for (int p = 0; p < 8; ++p) Bs[p*2 + kHalf][bpos] = bv[p];
        __syncthreads();
        #pragma unroll
        for (int kk = 0; kk < 16; ++kk) {
            float af[8], bf[8];
            *(float4*)&af[0] = *(const float4*)&As[kk][mIdx*4];
            *(float4*)&af[4] = *(const float4*)&As[kk][64 + mIdx*4];
            *(float4*)&bf[0] = *(const float4*)&Bs[kk][nIdx*4];
            *(float4*)&bf[4] = *(const float4*)&Bs[kk][64 + nIdx*4];
            #pragma unroll
            for (int i = 0; i < 8; ++i)
                #pragma unroll
                for (int j = 0; j < 8; ++j)
                    acc[i][j] += af[i]*bf[j];
        }
    }

    #pragma unroll
    for (int j = 0; j < 8; ++j) {
        int n = n0 + nIdx*8 + j;
        int b = n / OUT3;
        int s = n - b*OUT3;
        float* o = out + ((size_t)b*256 + co0 + mIdx*8)*OUT3 + s;
        #pragma unroll
        for (int i = 0; i < 8; ++i)
            atomicAdd(o + (size_t)i*OUT3, acc[i][j]);
    }
}

// ---------------- bias + relu epilogue ----------------
template<int OUT3>
__global__ __launch_bounds__(256)
void k_biasrelu(float* __restrict__ buf, const float* __restrict__ bias, int total)
{
    int g = blockIdx.x*256 + threadIdx.x;
    if (g >= total) return;
    int co = (g / OUT3) & 255;
    buf[g] = fmaxf(buf[g] + bias[co], 0.f);
}

// ---------------- squash primary capsules ----------------
__global__ __launch_bounds__(256)
void k_squash_u(const float* __restrict__ p_buf, const float* __restrict__ pbias,
                float* __restrict__ u)
{
    int g = blockIdx.x*256 + threadIdx.x;      // B*2048 = 4096
    int b = g >> 11;
    int i = g & 2047;
    int cap = i >> 6;
    int s   = i & 63;
    float vals[8];
    float sq = 0.f;
    #pragma unroll
    for (int c = 0; c < 8; ++c) {
        float x = p_buf[((size_t)(b*256) + cap*8 + c)*64 + s] + pbias[cap*8 + c];
        vals[c] = x;
        sq += x*x;
    }
    float scale = (sq / (1.f + sq)) / sqrtf(sq + 1e-8f);
    #pragma unroll
    for (int c = 0; c < 8; ++c) u[(size_t)g*8 + c] = vals[c]*scale;
}

// ---------------- routing ----------------
__global__ __launch_bounds__(256)
void k_route(const float* __restrict__ Wr, const float* __restrict__ u,
             float* __restrict__ s_buf)
{
    int j  = blockIdx.x;          // 50
    int i0 = blockIdx.y * 512;    // 4 splits
    __shared__ float us[2*512*8];
    for (int idx = threadIdx.x; idx < 8192; idx += 256) {
        int b = idx >> 12;
        us[idx] = u[(size_t)b*16384 + (size_t)i0*8 + (idx & 4095)];
    }
    __syncthreads();
    int tid = threadIdx.x;
    int cc  = tid & 7;
    const float* Wj = Wr + (size_t)j*2048*512 + (size_t)i0*512;
    float a00 = 0.f, a01 = 0.f, a10 = 0.f, a11 = 0.f;
    for (int i = 0; i < 512; ++i) {
        float w0 = Wj[(size_t)i*512 + tid];
        float w1 = Wj[(size_t)i*512 + tid + 256];
        float u0 = us[i*8 + cc];
        float u1 = us[4096 + i*8 + cc];
        a00 += w0*u0; a01 += w1*u0; a10 += w0*u1; a11 += w1*u1;
    }
    __syncthreads();
    float* red = us;
    red[tid] = a00; red[256 + tid] = a01; red[512 + tid] = a10; red[768 + tid] = a11;
    __syncthreads();
    if (tid < 128) {
        int b = tid >> 6, d = tid & 63;
        const float* rb = red + b*512 + (d >> 5)*256 + (d & 31)*8;
        float s = 0.f;
        #pragma unroll
        for (int c2 = 0; c2 < 8; ++c2) s += rb[c2];
        atomicAdd(&s_buf[((size_t)b*50 + j)*64 + d], s * (1.0f/50.0f));
    }
}

// ---------------- squash v ----------------
__global__ __launch_bounds__(64)
void k_squash_v(const float* __restrict__ s_buf, float* __restrict__ v_buf)
{
    int row = blockIdx.x;
    int d   = threadIdx.x;
    float s  = s_buf[row*64 + d];
    float sq = s*s;
    #pragma unroll
    for (int o = 32; o > 0; o >>= 1) sq += __shfl_xor(sq, o);
    float scale = (sq / (1.f + sq)) / sqrtf(sq + 1e-8f);
    v_buf[row*64 + d] = s*scale;
}

// ---------------- dec1 ----------------
__global__ __launch_bounds__(256)
void k_dec1(const float* __restrict__ v, const float* __restrict__ W,
            const float* __restrict__ bias, float* __restrict__ d1)
{
    int g  = blockIdx.x*256 + threadIdx.x;  // B*128*1728
    int o  = g % 1728;
    int co = (g / 1728) & 127;
    int b  = g / (1728*128);
    int ox = o / 144, oy = (o/12) % 12, oz = o % 12;
    int ix = ox/3, ka = ox - 3*ix;
    int iy = oy/3, kb = oy - 3*iy;
    int iz = oz/3, kc = oz - 3*iz;
    int widx = ka*9 + kb*3 + kc;
    int sidx = ix*16 + iy*4 + iz;
    float s = 0.f;
    for (int ci = 0; ci < 50; ++ci)
        s += v[((size_t)b*50 + ci)*64 + sidx] * W[((size_t)ci*128 + co)*27 + widx];
    d1[g] = fmaxf(s + bias[co], 0.f);
}

// ---------------- dec2 weight transpose: W(ci,co,kid) -> Wt[(kid*128+ci)*512+co] ----------------
__global__ __launch_bounds__(256)
void k_wt_dec2(const float* __restrict__ W, float* __restrict__ Wt)
{
    int g = blockIdx.x*256 + threadIdx.x;   // 27*128*512 = 1,769,472 exact
    int co = g & 511;
    int t  = g >> 9;
    int ci = t & 127;
    int kid = t >> 7;
    Wt[g] = W[((size_t)ci*512 + co)*27 + kid];
}

// ---------------- dec2: kid-major implicit GEMM, 128x128 ----------------
// d1: (B,128,12^3); Wt: [kid*128+ci][co]; out: (B, N3, 512)
__global__ __launch_bounds__(256, 2)
void k_dec2g(const float* __restrict__ d1, const float* __restrict__ Wt,
             const float* __restrict__ bias, float* __restrict__ out)
{
    const int tid  = threadIdx.x;
    const int mIdx = tid >> 4;
    const int nIdx = tid & 15;
    const int n0   = blockIdx.x * 128;   // over B*N3 = 27648
    const int co0  = blockIdx.y * 128;   // over 512

    __shared__ float As[16][132];
    __shared__ float Bs[16][132];

    const int nB    = n0 + (tid & 127);
    const int kHalf = tid >> 7;
    int b  = nB / N3;
    int s  = nB - b*N3;
    int ox = s / 576, oy = (s/24) % 24, oz = s % 24;
    const float* d1b = d1 + (size_t)b*128*1728;

    const int cB  = tid & 127;
    const int qB  = cB >> 2;
    const int bpos = ((((qB & 1) << 4) | (qB >> 1)) << 2) | (cB & 3);

    const int aRow  = tid >> 4;     // 0..15 (k within chunk)
    const int aTcol = tid & 15;

    float acc[8][8];
    #pragma unroll
    for (int i = 0; i < 8; ++i)
        #pragma unroll
        for (int j = 0; j < 8; ++j) acc[i][j] = 0.f;

    for (int kid = 0; kid < 27; ++kid) {
        int kd = kid/9, rr = kid - kd*9, kh = rr/3, kw = rr - kh*3;
        int tx = ox + 1 - kd, ty = oy + 1 - kh, tz = oz + 1 - kw;
        bool ok = (((tx | ty | tz) & 1) == 0) &&
                  ((unsigned)tx < 24u) && ((unsigned)ty < 24u) && ((unsigned)tz < 24u);
        const float* src = d1b + ((tx >> 1)*144 + (ty >> 1)*12 + (tz >> 1));
        #pragma unroll 1
        for (int cc = 0; cc < 8; ++cc) {
            const int k0 = kid*128 + cc*16;
            const float* wsrc = Wt + (size_t)(k0 + aRow)*512 + co0 + aTcol*8;
            float4 w0 = *(const float4*)wsrc;
            float4 w1 = *(const float4*)(wsrc + 4);
            float bv[8];
            #pragma unroll
            for (int p = 0; p < 8; ++p) {
                int ci = cc*16 + p*2 + kHalf;
                bv[p] = ok ? src[ci*1728] : 0.f;
            }
            __syncthreads();
            *(float4*)&As[aRow][aTcol*4]      = w0;
            *(float4*)&As[aRow][64 + aTcol*4] = w1;
            #pragma unroll
            for (int p = 0; p < 8; ++p) Bs[p*2 + kHalf][bpos] = bv[p];
            __syncthreads();
            #pragma unroll
            for (int kk = 0; kk < 16; ++kk) {
                float af[8], bf[8];
                *(float4*)&af[0] = *(const float4*)&As[kk][mIdx*4];
                *(float4*)&af[4] = *(const float4*)&As[kk][64 + mIdx*4];
                *(float4*)&bf[0] = *(const float4*)&Bs[kk][nIdx*4];
                *(float4*)&bf[4] = *(const float4*)&Bs[kk][64 + nIdx*4];
                #pragma unroll
                for (int i = 0; i < 8; ++i)
                    #pragma unroll
                    for (int j = 0; j < 8; ++j)
                        acc[i][j] += af[i]*bf[j];
            }
        }
    }

    float bb[8];
    #pragma unroll
    for (int i = 0; i < 8; ++i) bb[i] = bias[co0 + mIdx*8 + i];
    #pragma unroll
    for (int j = 0; j < 8; ++j) {
        int n = n0 + nIdx*8 + j;
        float* dst = out + (size_t)n*512 + co0 + mIdx*8;
        float4 v0, v1;
        v0.x = fmaxf(acc[0][j] + bb[0], 0.f);
        v0.y = fmaxf(acc[1][j] + bb[1], 0.f);
        v0.z = fmaxf(acc[2][j] + bb[2], 0.f);
        v0.w = fmaxf(acc[3][j] + bb[3], 0.f);
        v1.x = fmaxf(acc[4][j] + bb[4], 0.f);
        v1.y = fmaxf(acc[5][j] + bb[5], 0.f);
        v1.z = fmaxf(acc[6][j] + bb[6], 0.f);
        v1.w = fmaxf(acc[7][j] + bb[7], 0.f);
        *(float4*)dst       = v0;
        *(float4*)(dst + 4) = v1;
    }
}

// ---------------- final gather ----------------
__global__ __launch_bounds__(256)
void k_gather(const float* __restrict__ d2t, const int* __restrict__ vid,
              float* __restrict__ out)
{
    int g  = blockIdx.x*256 + threadIdx.x;
    int q  = g & 127;
    int bp = g >> 7;
    int v  = vid[bp];
    int b  = bp >> 13;
    float4 val = *(const float4*)&d2t[((size_t)b*N3 + v)*512 + q*4];
    *(float4*)&out[(size_t)bp*512 + q*4] = val;
}

extern "C" void kernel_launch(void* const* d_in, const int* in_sizes, int n_in,
                              void* d_out, int out_size, void* d_ws, size_t ws_size,
                              hipStream_t stream)
{
    (void)in_sizes; (void)n_in; (void)out_size; (void)ws_size;
    const float* pcl  = (const float*)d_in[0];
    const float* feat = (const float*)d_in[1];
    const float* c1w  = (const float*)d_in[3];
    const float* c1b  = (const float*)d_in[4];
    const float* c2w  = (const float*)d_in[5];
    const float* c2b  = (const float*)d_in[6];
    const float* pw   = (const float*)d_in[7];
    const float* pb   = (const float*)d_in[8];
    const float* rw   = (const float*)d_in[9];
    const float* d1w  = (const float*)d_in[10];
    const float* d1b_ = (const float*)d_in[11];
    const float* d2w  = (const float*)d_in[12];
    const float* d2b  = (const float*)d_in[13];

    char* ws = (char*)d_ws;
    float* d2t   = (float*)ws;                      // [0, 56,623,104) aliases mesh/h1/h2
    float* meshS = (float*)ws;                      // 14,155,776 B
    float* meshT = (float*)(ws + 14155776);         // 14,155,776 B
    float* h1    = (float*)(ws + 28311552);         // 16,384,000 B
    float* h2    = (float*)(ws + 44695552);         //  8,388,608 B
    char* tail = ws + 56623104;
    int*   vid   = (int*)tail;        tail += 65536;
    float* p_buf = (float*)tail;      tail += 131072;
    float* u_buf = (float*)tail;      tail += 131072;
    float* s_buf = (float*)tail;      tail += 25600;
    float* v_buf = (float*)tail;      tail += 25600;
    float* d1    = (float*)tail;      tail += 1769472;
    float* wt2   = (float*)tail;      tail += 7077888;   // dec2 transposed weights

    k_vid<<<dim3(B_), dim3(256), 0, stream>>>(pcl, vid);
    k_wt_dec2<<<dim3(6912), dim3(256), 0, stream>>>(d2w, wt2);

    hipMemsetAsync(meshS, 0, 14155776, stream);
    k_scatter<<<dim3(8192), dim3(256), 0, stream>>>(feat, vid, meshS);
    k_transpose<<<dim3(432, 4, 2), dim3(256), 0, stream>>>(meshS, meshT);

    // conv1: 128->256, k5, 24^3 -> 20^3
    hipMemsetAsync(h1, 0, 16384000, stream);
    k_gemm_conv<128,5,1,24,20><<<dim3(125, 2, 8), dim3(256), 0, stream>>>(meshT, c1w, h1);
    k_biasrelu<8000><<<dim3(16000), dim3(256), 0, stream>>>(h1, c1b, 4096000);

    // conv2: 256->256, k5, 20^3 -> 16^3
    hipMemsetAsync(h2, 0, 8388608, stream);
    k_gemm_conv<256,5,1,20,16><<<dim3(64, 2, 8), dim3(256), 0, stream>>>(h1, c2w, h2);
    k_biasrelu<4096><<<dim3(8192), dim3(256), 0, stream>>>(h2, c2b, 2097152);

    // primary caps: 256->256, k9, s2, 16^3 -> 4^3, splitk 216 (54 chunks each)
    hipMemsetAsync(p_buf, 0, 131072, stream);
    k_gemm_conv<256,9,2,16,4><<<dim3(1, 2, 216), dim3(256), 0, stream>>>(h2, pw, p_buf);

    k_squash_u<<<dim3(16), dim3(256), 0, stream>>>(p_buf, pb, u_buf);

    hipMemsetAsync(s_buf, 0, 25600, stream);
    k_route<<<dim3(50, 4), dim3(256), 0, stream>>>(rw, u_buf, s_buf);
    k_squash_v<<<dim3(100), dim3(64), 0, stream>>>(s_buf, v_buf);

    k_dec1<<<dim3(1728), dim3(256), 0, stream>>>(v_buf, d1w, d1b_, d1);
    k_dec2g<<<dim3(216, 4), dim3(256), 0, stream>>>(d1, wt2, d2b, d2t);

    k_gather<<<dim3(8192), dim3(256), 0, stream>>>(d2t, vid, (float*)d_out);
}

// Round 4
// 3547.506 us; speedup vs baseline: 2.7619x; 1.6056x over previous
//
#include <hip/hip_runtime.h>
#include <cstdint>
#include <cstddef>

typedef _Float16 h8 __attribute__((ext_vector_type(8)));
typedef _Float16 h4 __attribute__((ext_vector_type(4)));
typedef float    f32x4 __attribute__((ext_vector_type(4)));

#define B_   2
#define P_   8192
#define NVOX 24
#define N3   13824

// ---- workspace layout (bytes). Peak 63,883,264 < 65,849,344 proven in r3. ----
#define WB_OFF    0ull            // 24,772,608  (Wb1 24,576,000 / Wb2half 24,772,608)
#define H1CL_OFF  24772608ull     // 24,576,000  -> 49,348,608
#define MESHS_OFF 49348608ull     // 14,155,776  -> 63,504,384
#define D2H_OFF   0ull            // 28,311,552  (dec2 half-output; Wb/h1cl dead)
#define WT2_OFF   28311552ull     //  7,077,888  -> 35,389,440 (inside dead h1cl span)
#define H2_OFF    49348608ull     //  8,388,608  (inside dead meshS span)
#define D1_OFF    57737216ull     //  1,769,472
#define VID_OFF   63504384ull
#define PBUF_OFF  63569920ull
#define UBUF_OFF  63700992ull
#define SBUF_OFF  63832064ull
#define VBUF_OFF  63857664ull

// ---------------- helpers ----------------
__device__ inline void split3(float x, _Float16& a0, _Float16& a1, _Float16& a2)
{
    a0 = (_Float16)x;
    float r = x - (float)a0;
    a1 = (_Float16)(r * 2048.0f);
    float r2 = r - (float)a1 * 4.8828125e-4f;
    a2 = (_Float16)(r2 * 4194304.0f);
}

__device__ inline void gload16(const void* g, void* l)
{
    __builtin_amdgcn_global_load_lds(
        (const __attribute__((address_space(1))) char*)g,
        (__attribute__((address_space(3))) char*)l, 16, 0, 0);
}

// ---------------- voxel ids ----------------
__global__ __launch_bounds__(256)
void k_vid(const float* __restrict__ pcl, int* __restrict__ vid)
{
    int b = blockIdx.x;
    const float* pb = pcl + (size_t)b * P_ * 3;
    float mn[3] = {3e38f, 3e38f, 3e38f};
    float mx[3] = {-3e38f, -3e38f, -3e38f};
    for (int p = threadIdx.x; p < P_; p += 256) {
        #pragma unroll
        for (int d = 0; d < 3; ++d) {
            float v = pb[p*3 + d];
            mn[d] = fminf(mn[d], v);
            mx[d] = fmaxf(mx[d], v);
        }
    }
    __shared__ float red[6][256];
    #pragma unroll
    for (int d = 0; d < 3; ++d) { red[d][threadIdx.x] = mn[d]; red[3+d][threadIdx.x] = mx[d]; }
    __syncthreads();
    for (int s = 128; s > 0; s >>= 1) {
        if (threadIdx.x < (unsigned)s) {
            #pragma unroll
            for (int d = 0; d < 3; ++d) {
                red[d][threadIdx.x]   = fminf(red[d][threadIdx.x],   red[d][threadIdx.x + s]);
                red[3+d][threadIdx.x] = fmaxf(red[3+d][threadIdx.x], red[3+d][threadIdx.x + s]);
            }
        }
        __syncthreads();
    }
    float mn0 = red[0][0], mn1 = red[1][0], mn2 = red[2][0];
    float dd0 = red[3][0] - mn0 + 1e-9f;
    float dd1 = red[4][0] - mn1 + 1e-9f;
    float dd2 = red[5][0] - mn2 + 1e-9f;
    for (int p = threadIdx.x; p < P_; p += 256) {
        float fx = (pb[p*3+0] - mn0) / dd0 * 24.0f;
        float fy = (pb[p*3+1] - mn1) / dd1 * 24.0f;
        float fz = (pb[p*3+2] - mn2) / dd2 * 24.0f;
        int ix = (int)floorf(fx); ix = ix < 0 ? 0 : (ix > 23 ? 23 : ix);
        int iy = (int)floorf(fy); iy = iy < 0 ? 0 : (iy > 23 ? 23 : iy);
        int iz = (int)floorf(fz); iz = iz < 0 ? 0 : (iz > 23 ? 23 : iz);
        vid[b*P_ + p] = ix*576 + iy*24 + iz;
    }
}

// ---------------- scatter-add point features -> meshS (B, N3, 128) ----------------
__global__ __launch_bounds__(256)
void k_scatter(const float* __restrict__ feat, const int* __restrict__ vid,
               float* __restrict__ meshS)
{
    int g = blockIdx.x*256 + threadIdx.x;      // B*P*C = 2,097,152
    int c  = g & 127;
    int bp = g >> 7;
    int v  = vid[bp];
    int b  = bp >> 13;
    atomicAdd(&meshS[((size_t)b*N3 + v)*128 + c], feat[g]);
}

// ---------------- pre-split conv1 weights into blocked swizzled fp16x3 image ----------------
// Wb1 tile (m,c): 49152 B = 3 planes x [128 co][64 k] rows of 128 B, in-row byte ^ ((co&7)<<4)
__global__ __launch_bounds__(256)
void k_splitw1(const float* __restrict__ W, char* __restrict__ Wb)
{
    int g = blockIdx.x*256 + threadIdx.x;   // 4,096,000
    int el   = g & 8191;
    int tile = g >> 13;                      // m*250 + c
    int m = tile / 250, c = tile - m*250;
    int co = el >> 6, kl = el & 63;
    int kg = c*64 + kl;                      // K order: kid-major, ci-minor
    int kid = kg >> 7, ci = kg & 127;
    float x = W[((size_t)((m*128 + co)*128 + ci))*125 + kid];
    _Float16 a0, a1, a2; split3(x, a0, a1, a2);
    char* dst = Wb + (size_t)tile*49152 + (co*128 + ((kl*2) ^ ((co&7)<<4)));
    *(_Float16*)(dst)         = a0;
    *(_Float16*)(dst + 16384) = a1;
    *(_Float16*)(dst + 32768) = a2;
}

// ---------------- pre-split conv2 weights (half-K at a time) ----------------
__global__ __launch_bounds__(256)
void k_splitw2(const float* __restrict__ W, char* __restrict__ Wb, int cBase, int NC)
{
    int g = blockIdx.x*256 + threadIdx.x;   // 2*NC*8192
    int el   = g & 8191;
    int tile = g >> 13;                      // m*NC + cl
    int m = tile / NC, cl = tile - m*NC;
    int c = cBase + cl;
    int co = el >> 6, kl = el & 63;
    int kg = c*64 + kl;
    int kid = kg >> 8, ci = kg & 255;
    float x = W[((size_t)((m*128 + co)*256 + ci))*125 + kid];
    _Float16 a0, a1, a2; split3(x, a0, a1, a2);
    char* dst = Wb + (size_t)tile*49152 + (co*128 + ((kl*2) ^ ((co&7)<<4)));
    *(_Float16*)(dst)         = a0;
    *(_Float16*)(dst + 16384) = a1;
    *(_Float16*)(dst + 32768) = a2;
}

// ---------------- conv1 MFMA: 128->256, k5, 24^3 -> 20^3 ----------------
// A: Wb1 via global_load_lds. B: fp32 meshS, split in kernel, ds_write swizzled.
// Block 128(M) x 64(N), BK=64, 4 waves (2x2), wave tile 64x32 (4x2 frags 16x16x32).
// Output: h1cl fp16x3 planes, layout [b][sp20][ci] (channel-last) for conv2 staging.
__global__ __launch_bounds__(256, 2)
void k_conv1(const float* __restrict__ meshS, const char* __restrict__ Wb,
             const float* __restrict__ bias, _Float16* __restrict__ h1cl)
{
    extern __shared__ char lds[];           // 49152 (A) + 24576 (B) = 73728
    const int tid = threadIdx.x;
    const int l   = tid & 63;
    const int w   = tid >> 6;
    const int wm  = w >> 1, wn = w & 1;
    const int n0  = blockIdx.x * 64;
    const int m   = blockIdx.y;

    // B staging coords: thread -> n = tid&63, ci-quarter q = tid>>6
    const int q   = tid >> 6;
    const int nT  = n0 + (tid & 63);
    const int bB  = nT / 8000;
    const int soT = nT - bB*8000;
    const int xT = soT/400, yT = (soT/20)%20, zT = soT%20;
    const float* bsrc = meshS + ((size_t)(bB*13824 + xT*576 + yT*24 + zT))*128;
    const int nRow = tid & 63;
    const int bw0 = 49152 + nRow*128 + ((q*32)      ^ ((nRow&7)<<4));
    const int bw1 = 49152 + nRow*128 + ((q*32 + 16) ^ ((nRow&7)<<4));

    // frag-read per-lane base (row (l&15), k-quarter (l>>4), swizzle ((l&7)<<4))
    const int swz = (l & 7) << 4;
    const int qo  = (l >> 4) << 4;
    const int plF = (l & 15)*128 + (qo ^ (swz & 0x30)) + (swz & 0x40);

    f32x4 acc0[4][2], acc1[4][2], acc2[4][2];
    const f32x4 zz = {0.f, 0.f, 0.f, 0.f};
    #pragma unroll
    for (int a = 0; a < 4; ++a)
        #pragma unroll
        for (int b = 0; b < 2; ++b) { acc0[a][b] = zz; acc1[a][b] = zz; acc2[a][b] = zz; }

    for (int c = 0; c < 250; ++c) {
        int kid = c >> 1;
        int kd = kid/25, rr = kid - kd*25, kh = rr/5, kw = rr - kh*5;
        int koff = (kd*576 + kh*24 + kw)*128 + (c & 1)*64;
        const float* src = bsrc + koff + q*16;
        float fv[16];
        *(float4*)&fv[0]  = *(const float4*)(src);
        *(float4*)&fv[4]  = *(const float4*)(src + 4);
        *(float4*)&fv[8]  = *(const float4*)(src + 8);
        *(float4*)&fv[12] = *(const float4*)(src + 12);

        __syncthreads();   // prev-stage reads done
        {
            const char* wsrc = (const char*)Wb + ((size_t)(m*250 + c))*49152 + w*12288;
            #pragma unroll
            for (int i = 0; i < 12; ++i)
                gload16(wsrc + i*1024 + l*16, lds + w*12288 + i*1024);
        }
        {
            h8 p0[2], p1[2], p2[2];
            #pragma unroll
            for (int s = 0; s < 2; ++s)
                #pragma unroll
                for (int e = 0; e < 8; ++e) {
                    _Float16 t0, t1, t2; split3(fv[s*8+e], t0, t1, t2);
                    p0[s][e] = t0; p1[s][e] = t1; p2[s][e] = t2;
                }
            *(h8*)(lds + bw0)          = p0[0]; *(h8*)(lds + bw1)          = p0[1];
            *(h8*)(lds + 8192  + bw0)  = p1[0]; *(h8*)(lds + 8192  + bw1)  = p1[1];
            *(h8*)(lds + 16384 + bw0)  = p2[0]; *(h8*)(lds + 16384 + bw1)  = p2[1];
        }
        __syncthreads();   // staging complete

        #pragma unroll
        for (int ks = 0; ks < 2; ++ks) {
            const int kx = ks ? 64 : 0;
            h8 af[3][4], bf[3][2];
            #pragma unroll
            for (int v = 0; v < 3; ++v) {
                #pragma unroll
                for (int mf = 0; mf < 4; ++mf)
                    af[v][mf] = *(const h8*)(lds + v*16384 + (wm*64 + mf*16)*128 + (plF ^ kx));
                #pragma unroll
                for (int nf = 0; nf < 2; ++nf)
                    bf[v][nf] = *(const h8*)(lds + 49152 + v*8192 + (wn*32 + nf*16)*128 + (plF ^ kx));
            }
            #pragma unroll
            for (int mf = 0; mf < 4; ++mf)
                #pragma unroll
                for (int nf = 0; nf < 2; ++nf) {
                    acc0[mf][nf] = __builtin_amdgcn_mfma_f32_16x16x32_f16(af[0][mf], bf[0][nf], acc0[mf][nf], 0,0,0);
                    acc1[mf][nf] = __builtin_amdgcn_mfma_f32_16x16x32_f16(af[0][mf], bf[1][nf], acc1[mf][nf], 0,0,0);
                    acc1[mf][nf] = __builtin_amdgcn_mfma_f32_16x16x32_f16(af[1][mf], bf[0][nf], acc1[mf][nf], 0,0,0);
                    acc2[mf][nf] = __builtin_amdgcn_mfma_f32_16x16x32_f16(af[0][mf], bf[2][nf], acc2[mf][nf], 0,0,0);
                    acc2[mf][nf] = __builtin_amdgcn_mfma_f32_16x16x32_f16(af[1][mf], bf[1][nf], acc2[mf][nf], 0,0,0);
                    acc2[mf][nf] = __builtin_amdgcn_mfma_f32_16x16x32_f16(af[2][mf], bf[0][nf], acc2[mf][nf], 0,0,0);
                }
        }
    }

    const float s1 = 4.8828125e-04f, s2 = 2.384185791015625e-07f;
    #pragma unroll
    for (int mf = 0; mf < 4; ++mf)
        #pragma unroll
        for (int nf = 0; nf < 2; ++nf) {
            f32x4 r = acc0[mf][nf] + s1*acc1[mf][nf] + s2*acc2[mf][nf];
            int co = m*128 + wm*64 + mf*16 + ((l>>4)<<2);
            int n  = n0 + wn*32 + nf*16 + (l&15);
            size_t base = (size_t)n*256 + co;   // [b][sp][ci] flat = n*256 + co
            h4 v0, v1, v2;
            #pragma unroll
            for (int rr = 0; rr < 4; ++rr) {
                float x = fmaxf(r[rr] + bias[co + rr], 0.f);
                _Float16 t0, t1, t2; split3(x, t0, t1, t2);
                v0[rr] = t0; v1[rr] = t1; v2[rr] = t2;
            }
            *(h4*)(h1cl + base)           = v0;
            *(h4*)(h1cl + 4096000 + base) = v1;
            *(h4*)(h1cl + 8192000 + base) = v2;
        }
}

// ---------------- conv2 MFMA: 256->256, k5, 20^3 -> 16^3, two sequential K-halves ----------------
__global__ __launch_bounds__(256, 2)
void k_conv2(const _Float16* __restrict__ h1cl, const char* __restrict__ Wb,
             const float* __restrict__ bias, float* __restrict__ h2,
             int cBase, int NSt, int accum)
{
    extern __shared__ char lds[];
    const int tid = threadIdx.x;
    const int l   = tid & 63;
    const int w   = tid >> 6;
    const int wm  = w >> 1, wn = w & 1;
    const int n0  = blockIdx.x * 64;
    const int m   = blockIdx.y;

    // B gload source precompute (6 insts/wave), inverse-swizzled per-lane addresses
    const _Float16* preP[6];
    #pragma unroll
    for (int i = 0; i < 6; ++i) {
        int g   = w*6144 + i*1024 + l*16;
        int ver = g >> 13;
        int dd  = g & 8191;
        int nl  = dd >> 7;
        int lg  = (dd & 127) ^ ((nl & 7) << 4);
        int klocal = lg >> 1;
        int n = n0 + nl;
        int b2 = n >> 12, so = n & 4095;
        int x = so >> 8, y = (so >> 4) & 15, z = so & 15;
        preP[i] = h1cl + (size_t)ver*4096000
                       + ((size_t)(b2*8000 + x*400 + y*20 + z))*256 + klocal;
    }

    const int swz = (l & 7) << 4;
    const int qo  = (l >> 4) << 4;
    const int plF = (l & 15)*128 + (qo ^ (swz & 0x30)) + (swz & 0x40);

    f32x4 acc0[4][2], acc1[4][2], acc2[4][2];
    const f32x4 zz = {0.f, 0.f, 0.f, 0.f};
    #pragma unroll
    for (int a = 0; a < 4; ++a)
        #pragma unroll
        for (int b = 0; b < 2; ++b) { acc0[a][b] = zz; acc1[a][b] = zz; acc2[a][b] = zz; }

    for (int c = 0; c < NSt; ++c) {
        int cg = cBase + c;
        int kid = cg >> 2;
        int kd = kid/25, rr = kid - kd*25, kh = rr/5, kw = rr - kh*5;
        int koff = (kd*400 + kh*20 + kw)*256 + (cg & 3)*64;

        __syncthreads();
        {
            const char* wsrc = (const char*)Wb + ((size_t)(m*NSt + c))*49152 + w*12288;
            #pragma unroll
            for (int i = 0; i < 12; ++i)
                gload16(wsrc + i*1024 + l*16, lds + w*12288 + i*1024);
            #pragma unroll
            for (int i = 0; i < 6; ++i)
                gload16(preP[i] + koff, lds + 49152 + w*6144 + i*1024);
        }
        __syncthreads();

        #pragma unroll
        for (int ks = 0; ks < 2; ++ks) {
            const int kx = ks ? 64 : 0;
            h8 af[3][4], bf[3][2];
            #pragma unroll
            for (int v = 0; v < 3; ++v) {
                #pragma unroll
                for (int mf = 0; mf < 4; ++mf)
                    af[v][mf] = *(const h8*)(lds + v*16384 + (wm*64 + mf*16)*128 + (plF ^ kx));
                #pragma unroll
                for (int nf = 0; nf < 2; ++nf)
                    bf[v][nf] = *(const h8*)(lds + 49152 + v*8192 + (wn*32 + nf*16)*128 + (plF ^ kx));
            }
            #pragma unroll
            for (int mf = 0; mf < 4; ++mf)
                #pragma unroll
                for (int nf = 0; nf < 2; ++nf) {
                    acc0[mf][nf] = __builtin_amdgcn_mfma_f32_16x16x32_f16(af[0][mf], bf[0][nf], acc0[mf][nf], 0,0,0);
                    acc1[mf][nf] = __builtin_amdgcn_mfma_f32_16x16x32_f16(af[0][mf], bf[1][nf], acc1[mf][nf], 0,0,0);
                    acc1[mf][nf] = __builtin_amdgcn_mfma_f32_16x16x32_f16(af[1][mf], bf[0][nf], acc1[mf][nf], 0,0,0);
                    acc2[mf][nf] = __builtin_amdgcn_mfma_f32_16x16x32_f16(af[0][mf], bf[2][nf], acc2[mf][nf], 0,0,0);
                    acc2[mf][nf] = __builtin_amdgcn_mfma_f32_16x16x32_f16(af[1][mf], bf[1][nf], acc2[mf][nf], 0,0,0);
                    acc2[mf][nf] = __builtin_amdgcn_mfma_f32_16x16x32_f16(af[2][mf], bf[0][nf], acc2[mf][nf], 0,0,0);
                }
        }
    }

    const float s1 = 4.8828125e-04f, s2 = 2.384185791015625e-07f;
    #pragma unroll
    for (int mf = 0; mf < 4; ++mf)
        #pragma unroll
        for (int nf = 0; nf < 2; ++nf) {
            f32x4 r = acc0[mf][nf] + s1*acc1[mf][nf] + s2*acc2[mf][nf];
            int co = m*128 + wm*64 + mf*16 + ((l>>4)<<2);
            int n  = n0 + wn*32 + nf*16 + (l&15);
            int b2 = n >> 12, so = n & 4095;
            #pragma unroll
            for (int rr = 0; rr < 4; ++rr) {
                size_t idx = ((size_t)(b2*256 + co + rr))*4096 + so;
                if (accum) h2[idx] = fmaxf(r[rr] + h2[idx] + bias[co + rr], 0.f);
                else       h2[idx] = r[rr];
            }
        }
}

// ---------------- fp32 implicit-GEMM conv (kept for primary caps only) ----------------
template<int CIN, int KD, int STRIDE, int IND, int OUTD>
__global__ __launch_bounds__(256, 2)
void k_gemm_conv(const float* __restrict__ in, const float* __restrict__ W,
                 float* __restrict__ out)
{
    constexpr int KD2  = KD*KD;
    constexpr int K3   = KD*KD*KD;
    constexpr int IND2 = IND*IND;
    constexpr int IND3 = IND2*IND;
    constexpr int OUT2 = OUTD*OUTD;
    constexpr int OUT3 = OUT2*OUTD;
    constexpr int KTOT = CIN*K3;
    constexpr int NCH  = KTOT/16;

    const int tid  = threadIdx.x;
    const int mIdx = tid >> 4;
    const int nIdx = tid & 15;
    const int n0   = blockIdx.x * 128;
    const int co0  = blockIdx.y * 128;
    const int per  = NCH / (int)gridDim.z;
    const int c0   = blockIdx.z * per;
    const int c1   = c0 + per;

    __shared__ float As[16][132];
    __shared__ float Bs[16][132];

    const int nB    = n0 + (tid & 127);
    const int kHalf = tid >> 7;
    int bB = nB / OUT3;
    int sB = nB - bB*OUT3;
    int xB = sB / OUT2;
    int yB = (sB / OUTD) % OUTD;
    int zB = sB % OUTD;
    const float* inB = in + (size_t)bB*CIN*IND3
                          + (xB*STRIDE)*IND2 + (yB*STRIDE)*IND + (zB*STRIDE);
    const int cB  = tid & 127;
    const int qB  = cB >> 2;
    const int bpos = ((((qB & 1) << 4) | (qB >> 1)) << 2) | (cB & 3);

    const int aCo = tid >> 2;
    const int aKq = (tid & 3) * 4;
    const int qA  = aCo >> 2;
    const int apos = ((((qA & 1) << 4) | (qA >> 1)) << 2) | (aCo & 3);
    const float* Wr0 = W + (size_t)(co0 + aCo)*KTOT + aKq;
    const float* Wr1 = W + (size_t)(co0 + 64 + aCo)*KTOT + aKq;

    float acc[8][8];
    #pragma unroll
    for (int i = 0; i < 8; ++i)
        #pragma unroll
        for (int j = 0; j < 8; ++j) acc[i][j] = 0.f;

    for (int c = c0; c < c1; ++c) {
        const int kb = c*16;
        float4 a0 = *(const float4*)(Wr0 + kb);
        float4 a1 = *(const float4*)(Wr1 + kb);
        float bv[8];
        #pragma unroll
        for (int p = 0; p < 8; ++p) {
            int k  = kb + p*2 + kHalf;
            int ci = k / K3;
            int r  = k - ci*K3;
            int kd = r / KD2;
            int r2 = r - kd*KD2;
            int kh = r2 / KD;
            int kw = r2 - kh*KD;
            bv[p] = inB[ci*IND3 + kd*IND2 + kh*IND + kw];
        }
        __syncthreads();
        As[aKq+0][apos] = a0.x; As[aKq+1][apos] = a0.y;
        As[aKq+2][apos] = a0.z; As[aKq+3][apos] = a0.w;
        As[aKq+0][apos+32] = a1.x; As[aKq+1][apos+32] = a1.y;
        As[aKq+2][apos+32] = a1.z; As[aKq+3][apos+32] = a1.w;
        #pragma unroll
        for (int p = 0; p < 8; ++p) Bs[p*2 + kHalf][bpos] = bv[p];
        __syncthreads();
        #pragma unroll
        for (int kk = 0; kk < 16; ++kk) {
            float af[8], bf[8];
            *(float4*)&af[0] = *(const float4*)&As[kk][mIdx*4];
            *(float4*)&af[4] = *(const float4*)&As[kk][64 + mIdx*4];
            *(float4*)&bf[0] = *(const float4*)&Bs[kk][nIdx*4];
            *(float4*)&bf[4] = *(const float4*)&Bs[kk][64 + nIdx*4];
            #pragma unroll
            for (int i = 0; i < 8; ++i)
                #pragma unroll
                for (int j = 0; j < 8; ++j)
                    acc[i][j] += af[i]*bf[j];
        }
    }

    #pragma unroll
    for (int j = 0; j < 8; ++j) {
        int n = n0 + nIdx*8 + j;
        int b = n / OUT3;
        int s = n - b*OUT3;
        float* o = out + ((size_t)b*256 + co0 + mIdx*8)*OUT3 + s;
        #pragma unroll
        for (int i = 0; i < 8; ++i)
            atomicAdd(o + (size_t)i*OUT3, acc[i][j]);
    }
}

// ---------------- squash primary capsules ----------------
__global__ __launch_bounds__(256)
void k_squash_u(const float* __restrict__ p_buf, const float* __restrict__ pbias,
                float* __restrict__ u)
{
    int g = blockIdx.x*256 + threadIdx.x;      // B*2048 = 4096
    int b = g >> 11;
    int i = g & 2047;
    int cap = i >> 6;
    int s   = i & 63;
    float vals[8];
    float sq = 0.f;
    #pragma unroll
    for (int c = 0; c < 8; ++c) {
        float x = p_buf[((size_t)(b*256) + cap*8 + c)*64 + s] + pbias[cap*8 + c];
        vals[c] = x;
        sq += x*x;
    }
    float scale = (sq / (1.f + sq)) / sqrtf(sq + 1e-8f);
    #pragma unroll
    for (int c = 0; c < 8; ++c) u[(size_t)g*8 + c] = vals[c]*scale;
}

// ---------------- routing ----------------
__global__ __launch_bounds__(256)
void k_route(const float* __restrict__ Wr, const float* __restrict__ u,
             float* __restrict__ s_buf)
{
    int j  = blockIdx.x;
    int i0 = blockIdx.y * 512;
    __shared__ float us[2*512*8];
    for (int idx = threadIdx.x; idx < 8192; idx += 256) {
        int b = idx >> 12;
        us[idx] = u[(size_t)b*16384 + (size_t)i0*8 + (idx & 4095)];
    }
    __syncthreads();
    int tid = threadIdx.x;
    int cc  = tid & 7;
    const float* Wj = Wr + (size_t)j*2048*512 + (size_t)i0*512;
    float a00 = 0.f, a01 = 0.f, a10 = 0.f, a11 = 0.f;
    for (int i = 0; i < 512; ++i) {
        float w0 = Wj[(size_t)i*512 + tid];
        float w1 = Wj[(size_t)i*512 + tid + 256];
        float u0 = us[i*8 + cc];
        float u1 = us[4096 + i*8 + cc];
        a00 += w0*u0; a01 += w1*u0; a10 += w0*u1; a11 += w1*u1;
    }
    __syncthreads();
    float* red = us;
    red[tid] = a00; red[256 + tid] = a01; red[512 + tid] = a10; red[768 + tid] = a11;
    __syncthreads();
    if (tid < 128) {
        int b = tid >> 6, d = tid & 63;
        const float* rb = red + b*512 + (d >> 5)*256 + (d & 31)*8;
        float s = 0.f;
        #pragma unroll
        for (int c2 = 0; c2 < 8; ++c2) s += rb[c2];
        atomicAdd(&s_buf[((size_t)b*50 + j)*64 + d], s * (1.0f/50.0f));
    }
}

// ---------------- squash v ----------------
__global__ __launch_bounds__(64)
void k_squash_v(const float* __restrict__ s_buf, float* __restrict__ v_buf)
{
    int row = blockIdx.x;
    int d   = threadIdx.x;
    float s  = s_buf[row*64 + d];
    float sq = s*s;
    #pragma unroll
    for (int o = 32; o > 0; o >>= 1) sq += __shfl_xor(sq, o);
    float scale = (sq / (1.f + sq)) / sqrtf(sq + 1e-8f);
    v_buf[row*64 + d] = s*scale;
}

// ---------------- dec1 ----------------
__global__ __launch_bounds__(256)
void k_dec1(const float* __restrict__ v, const float* __restrict__ W,
            const float* __restrict__ bias, float* __restrict__ d1)
{
    int g  = blockIdx.x*256 + threadIdx.x;  // B*128*1728
    int o  = g % 1728;
    int co = (g / 1728) & 127;
    int b  = g / (1728*128);
    int ox = o / 144, oy = (o/12) % 12, oz = o % 12;
    int ix = ox/3, ka = ox - 3*ix;
    int iy = oy/3, kb = oy - 3*iy;
    int iz = oz/3, kc = oz - 3*iz;
    int widx = ka*9 + kb*3 + kc;
    int sidx = ix*16 + iy*4 + iz;
    float s = 0.f;
    for (int ci = 0; ci < 50; ++ci)
        s += v[((size_t)b*50 + ci)*64 + sidx] * W[((size_t)ci*128 + co)*27 + widx];
    d1[g] = fmaxf(s + bias[co], 0.f);
}

// ---------------- dec2 weight transpose ----------------
__global__ __launch_bounds__(256)
void k_wt_dec2(const float* __restrict__ W, float* __restrict__ Wt)
{
    int g = blockIdx.x*256 + threadIdx.x;   // 1,769,472
    int co = g & 511;
    int t  = g >> 9;
    int ci = t & 127;
    int kid = t >> 7;
    Wt[g] = W[((size_t)ci*512 + co)*27 + kid];
}

// ---------------- dec2: kid-major implicit GEMM, 128x128, per co-half ----------------
__global__ __launch_bounds__(256, 2)
void k_dec2g(const float* __restrict__ d1, const float* __restrict__ Wt,
             const float* __restrict__ bias, float* __restrict__ out, int coBase)
{
    const int tid  = threadIdx.x;
    const int mIdx = tid >> 4;
    const int nIdx = tid & 15;
    const int n0   = blockIdx.x * 128;
    const int co0  = coBase + blockIdx.y * 128;

    __shared__ float As[16][132];
    __shared__ float Bs[16][132];

    const int nB    = n0 + (tid & 127);
    const int kHalf = tid >> 7;
    int b  = nB / N3;
    int s  = nB - b*N3;
    int ox = s / 576, oy = (s/24) % 24, oz = s % 24;
    const float* d1b = d1 + (size_t)b*128*1728;

    const int cB  = tid & 127;
    const int qB  = cB >> 2;
    const int bpos = ((((qB & 1) << 4) | (qB >> 1)) << 2) | (cB & 3);

    const int aRow  = tid >> 4;
    const int aTcol = tid & 15;

    float acc[8][8];
    #pragma unroll
    for (int i = 0; i < 8; ++i)
        #pragma unroll
        for (int j = 0; j < 8; ++j) acc[i][j] = 0.f;

    for (int kid = 0; kid < 27; ++kid) {
        int kd = kid/9, rr = kid - kd*9, kh = rr/3, kw = rr - kh*3;
        int tx = ox + 1 - kd, ty = oy + 1 - kh, tz = oz + 1 - kw;
        bool ok = (((tx | ty | tz) & 1) == 0) &&
                  ((unsigned)tx < 24u) && ((unsigned)ty < 24u) && ((unsigned)tz < 24u);
        const float* src = d1b + ((tx >> 1)*144 + (ty >> 1)*12 + (tz >> 1));
        #pragma unroll 1
        for (int cc = 0; cc < 8; ++cc) {
            const int k0 = kid*128 + cc*16;
            const float* wsrc = Wt + (size_t)(k0 + aRow)*512 + co0 + aTcol*8;
            float4 w0 = *(const float4*)wsrc;
            float4 w1 = *(const float4*)(wsrc + 4);
            float bv[8];
            #pragma unroll
            for (int p = 0; p < 8; ++p) {
                int ci = cc*16 + p*2 + kHalf;
                bv[p] = ok ? src[ci*1728] : 0.f;
            }
            __syncthreads();
            *(float4*)&As[aRow][aTcol*4]      = w0;
            *(float4*)&As[aRow][64 + aTcol*4] = w1;
            #pragma unroll
            for (int p = 0; p < 8; ++p) Bs[p*2 + kHalf][bpos] = bv[p];
            __syncthreads();
            #pragma unroll
            for (int kk = 0; kk < 16; ++kk) {
                float af[8], bf[8];
                *(float4*)&af[0] = *(const float4*)&As[kk][mIdx*4];
                *(float4*)&af[4] = *(const float4*)&As[kk][64 + mIdx*4];
                *(float4*)&bf[0] = *(const float4*)&Bs[kk][nIdx*4];
                *(float4*)&bf[4] = *(const float4*)&Bs[kk][64 + nIdx*4];
                #pragma unroll
                for (int i = 0; i < 8; ++i)
                    #pragma unroll
                    for (int j = 0; j < 8; ++j)
                        acc[i][j] += af[i]*bf[j];
            }
        }
    }

    float bb[8];
    #pragma unroll
    for (int i = 0; i < 8; ++i) bb[i] = bias[co0 + mIdx*8 + i];
    #pragma unroll
    for (int j = 0; j < 8; ++j) {
        int n = n0 + nIdx*8 + j;
        float* dst = out + (size_t)n*256 + (co0 - coBase) + mIdx*8;
        float4 v0, v1;
        v0.x = fmaxf(acc[0][j] + bb[0], 0.f);
        v0.y = fmaxf(acc[1][j] + bb[1], 0.f);
        v0.z = fmaxf(acc[2][j] + bb[2], 0.f);
        v0.w = fmaxf(acc[3][j] + bb[3], 0.f);
        v1.x = fmaxf(acc[4][j] + bb[4], 0.f);
        v1.y = fmaxf(acc[5][j] + bb[5], 0.f);
        v1.z = fmaxf(acc[6][j] + bb[6], 0.f);
        v1.w = fmaxf(acc[7][j] + bb[7], 0.f);
        *(float4*)dst       = v0;
        *(float4*)(dst + 4) = v1;
    }
}

// ---------------- final gather (per co-half) ----------------
__global__ __launch_bounds__(256)
void k_gather(const float* __restrict__ d2h, const int* __restrict__ vid,
              float* __restrict__ out, int colOff)
{
    int g  = blockIdx.x*256 + threadIdx.x;   // B*P*64 float4 units
    int qq = g & 63;
    int bp = g >> 6;
    int v  = vid[bp];
    int b  = bp >> 13;
    float4 val = *(const float4*)&d2h[((size_t)(b*N3 + v))*256 + qq*4];
    *(float4*)&out[(size_t)bp*512 + colOff + qq*4] = val;
}

extern "C" void kernel_launch(void* const* d_in, const int* in_sizes, int n_in,
                              void* d_out, int out_size, void* d_ws, size_t ws_size,
                              hipStream_t stream)
{
    (void)in_sizes; (void)n_in; (void)out_size; (void)ws_size;
    const float* pcl  = (const float*)d_in[0];
    const float* feat = (const float*)d_in[1];
    const float* c1w  = (const float*)d_in[3];
    const float* c1b  = (const float*)d_in[4];
    const float* c2w  = (const float*)d_in[5];
    const float* c2b  = (const float*)d_in[6];
    const float* pw   = (const float*)d_in[7];
    const float* pb   = (const float*)d_in[8];
    const float* rw   = (const float*)d_in[9];
    const float* d1w  = (const float*)d_in[10];
    const float* d1b_ = (const float*)d_in[11];
    const float* d2w  = (const float*)d_in[12];
    const float* d2b  = (const float*)d_in[13];

    char* ws = (char*)d_ws;
    char*      Wb    = ws + WB_OFF;
    _Float16*  h1cl  = (_Float16*)(ws + H1CL_OFF);
    float*     meshS = (float*)(ws + MESHS_OFF);
    float*     d2h   = (float*)(ws + D2H_OFF);
    float*     wt2   = (float*)(ws + WT2_OFF);
    float*     h2    = (float*)(ws + H2_OFF);
    float*     d1    = (float*)(ws + D1_OFF);
    int*       vid   = (int*)(ws + VID_OFF);
    float*     p_buf = (float*)(ws + PBUF_OFF);
    float*     u_buf = (float*)(ws + UBUF_OFF);
    float*     s_buf = (float*)(ws + SBUF_OFF);
    float*     v_buf = (float*)(ws + VBUF_OFF);

    k_vid<<<dim3(B_), dim3(256), 0, stream>>>(pcl, vid);

    hipMemsetAsync(meshS, 0, 14155776, stream);
    k_scatter<<<dim3(8192), dim3(256), 0, stream>>>(feat, vid, meshS);

    // conv1
    k_splitw1<<<dim3(16000), dim3(256), 0, stream>>>(c1w, Wb);
    k_conv1<<<dim3(250, 2), dim3(256), 73728, stream>>>(meshS, Wb, c1b, h1cl);

    // conv2 in two K-halves (kid 0..61 | 62..124), shared weight slot
    k_splitw2<<<dim3(248*64), dim3(256), 0, stream>>>(c2w, Wb, 0, 248);
    k_conv2<<<dim3(128, 2), dim3(256), 73728, stream>>>(h1cl, Wb, c2b, h2, 0, 248, 0);
    k_splitw2<<<dim3(252*64), dim3(256), 0, stream>>>(c2w, Wb, 248, 252);
    k_conv2<<<dim3(128, 2), dim3(256), 73728, stream>>>(h1cl, Wb, c2b, h2, 248, 252, 1);

    // primary caps: fp32 path, splitk 216
    hipMemsetAsync(p_buf, 0, 131072, stream);
    k_gemm_conv<256,9,2,16,4><<<dim3(1, 2, 216), dim3(256), 0, stream>>>(h2, pw, p_buf);
    k_squash_u<<<dim3(16), dim3(256), 0, stream>>>(p_buf, pb, u_buf);

    hipMemsetAsync(s_buf, 0, 25600, stream);
    k_route<<<dim3(50, 4), dim3(256), 0, stream>>>(rw, u_buf, s_buf);
    k_squash_v<<<dim3(100), dim3(64), 0, stream>>>(s_buf, v_buf);

    k_dec1<<<dim3(1728), dim3(256), 0, stream>>>(v_buf, d1w, d1b_, d1);
    k_wt_dec2<<<dim3(6912), dim3(256), 0, stream>>>(d2w, wt2);

    k_dec2g<<<dim3(216, 2), dim3(256), 0, stream>>>(d1, wt2, d2b, d2h, 0);
    k_gather<<<dim3(4096), dim3(256), 0, stream>>>(d2h, vid, (float*)d_out, 0);
    k_dec2g<<<dim3(216, 2), dim3(256), 0, stream>>>(d1, wt2, d2b, d2h, 256);
    k_gather<<<dim3(4096), dim3(256), 0, stream>>>(d2h, vid, (float*)d_out, 256);
}

// Round 5
// 2818.098 us; speedup vs baseline: 3.4768x; 1.2588x over previous
//
#include <hip/hip_runtime.h>
#include <cstdint>
#include <cstddef>

typedef _Float16 h8 __attribute__((ext_vector_type(8)));
typedef _Float16 h4 __attribute__((ext_vector_type(4)));
typedef float    f32x4 __attribute__((ext_vector_type(4)));

#define B_   2
#define P_   8192
#define NVOX 24
#define N3   13824

// ---- workspace layout (bytes). Peak 63,883,264 (unchanged from r4). ----
#define WB_OFF    0ull            // conv weight image (24,772,608 max)
#define H1CL_OFF  24772608ull     // 24,576,000 -> 49,348,608
#define MESHS_OFF 49348608ull     // 14,155,776 -> 63,504,384
#define D2H_OFF   0ull            // 28,311,552 dec2 half-output (Wb/h1cl dead)
#define WB2_OFF   28311552ull     // 10,616,832 -> 38,928,384 (inside dead h1cl)
#define D1CL_OFF  38928384ull     //  2,654,208 -> 41,582,592 (inside dead h1cl)
#define H2_OFF    49348608ull     //  8,388,608 (inside dead meshS span)
#define VID_OFF   63504384ull
#define PBUF_OFF  63569920ull
#define UBUF_OFF  63700992ull
#define SBUF_OFF  63832064ull
#define VBUF_OFF  63857664ull

// ---------------- helpers ----------------
__device__ inline void split3(float x, _Float16& a0, _Float16& a1, _Float16& a2)
{
    a0 = (_Float16)x;
    float r = x - (float)a0;
    a1 = (_Float16)(r * 2048.0f);
    float r2 = r - (float)a1 * 4.8828125e-4f;
    a2 = (_Float16)(r2 * 4194304.0f);
}

__device__ inline void gload16(const void* g, void* l)
{
    __builtin_amdgcn_global_load_lds(
        (const __attribute__((address_space(1))) char*)g,
        (__attribute__((address_space(3))) char*)l, 16, 0, 0);
}

// ---------------- voxel ids ----------------
__global__ __launch_bounds__(256)
void k_vid(const float* __restrict__ pcl, int* __restrict__ vid)
{
    int b = blockIdx.x;
    const float* pb = pcl + (size_t)b * P_ * 3;
    float mn[3] = {3e38f, 3e38f, 3e38f};
    float mx[3] = {-3e38f, -3e38f, -3e38f};
    for (int p = threadIdx.x; p < P_; p += 256) {
        #pragma unroll
        for (int d = 0; d < 3; ++d) {
            float v = pb[p*3 + d];
            mn[d] = fminf(mn[d], v);
            mx[d] = fmaxf(mx[d], v);
        }
    }
    __shared__ float red[6][256];
    #pragma unroll
    for (int d = 0; d < 3; ++d) { red[d][threadIdx.x] = mn[d]; red[3+d][threadIdx.x] = mx[d]; }
    __syncthreads();
    for (int s = 128; s > 0; s >>= 1) {
        if (threadIdx.x < (unsigned)s) {
            #pragma unroll
            for (int d = 0; d < 3; ++d) {
                red[d][threadIdx.x]   = fminf(red[d][threadIdx.x],   red[d][threadIdx.x + s]);
                red[3+d][threadIdx.x] = fmaxf(red[3+d][threadIdx.x], red[3+d][threadIdx.x + s]);
            }
        }
        __syncthreads();
    }
    float mn0 = red[0][0], mn1 = red[1][0], mn2 = red[2][0];
    float dd0 = red[3][0] - mn0 + 1e-9f;
    float dd1 = red[4][0] - mn1 + 1e-9f;
    float dd2 = red[5][0] - mn2 + 1e-9f;
    for (int p = threadIdx.x; p < P_; p += 256) {
        float fx = (pb[p*3+0] - mn0) / dd0 * 24.0f;
        float fy = (pb[p*3+1] - mn1) / dd1 * 24.0f;
        float fz = (pb[p*3+2] - mn2) / dd2 * 24.0f;
        int ix = (int)floorf(fx); ix = ix < 0 ? 0 : (ix > 23 ? 23 : ix);
        int iy = (int)floorf(fy); iy = iy < 0 ? 0 : (iy > 23 ? 23 : iy);
        int iz = (int)floorf(fz); iz = iz < 0 ? 0 : (iz > 23 ? 23 : iz);
        vid[b*P_ + p] = ix*576 + iy*24 + iz;
    }
}

// ---------------- scatter-add point features -> meshS (B, N3, 128) ----------------
__global__ __launch_bounds__(256)
void k_scatter(const float* __restrict__ feat, const int* __restrict__ vid,
               float* __restrict__ meshS)
{
    int g = blockIdx.x*256 + threadIdx.x;      // B*P*C = 2,097,152
    int c  = g & 127;
    int bp = g >> 7;
    int v  = vid[bp];
    int b  = bp >> 13;
    atomicAdd(&meshS[((size_t)b*N3 + v)*128 + c], feat[g]);
}

// ---------------- pre-split conv1 weights into blocked swizzled fp16x3 image ----------------
__global__ __launch_bounds__(256)
void k_splitw1(const float* __restrict__ W, char* __restrict__ Wb)
{
    int g = blockIdx.x*256 + threadIdx.x;   // 4,096,000
    int el   = g & 8191;
    int tile = g >> 13;                      // m*250 + c
    int m = tile / 250, c = tile - m*250;
    int co = el >> 6, kl = el & 63;
    int kg = c*64 + kl;                      // K order: kid-major, ci-minor
    int kid = kg >> 7, ci = kg & 127;
    float x = W[((size_t)((m*128 + co)*128 + ci))*125 + kid];
    _Float16 a0, a1, a2; split3(x, a0, a1, a2);
    char* dst = Wb + (size_t)tile*49152 + (co*128 + ((kl*2) ^ ((co&7)<<4)));
    *(_Float16*)(dst)         = a0;
    *(_Float16*)(dst + 16384) = a1;
    *(_Float16*)(dst + 32768) = a2;
}

// ---------------- pre-split conv2 weights (half-K at a time) ----------------
__global__ __launch_bounds__(256)
void k_splitw2(const float* __restrict__ W, char* __restrict__ Wb, int cBase, int NC)
{
    int g = blockIdx.x*256 + threadIdx.x;   // 2*NC*8192
    int el   = g & 8191;
    int tile = g >> 13;                      // m*NC + cl
    int m = tile / NC, cl = tile - m*NC;
    int c = cBase + cl;
    int co = el >> 6, kl = el & 63;
    int kg = c*64 + kl;
    int kid = kg >> 8, ci = kg & 255;
    float x = W[((size_t)((m*128 + co)*256 + ci))*125 + kid];
    _Float16 a0, a1, a2; split3(x, a0, a1, a2);
    char* dst = Wb + (size_t)tile*49152 + (co*128 + ((kl*2) ^ ((co&7)<<4)));
    *(_Float16*)(dst)         = a0;
    *(_Float16*)(dst + 16384) = a1;
    *(_Float16*)(dst + 32768) = a2;
}

// ---------------- pre-split dec2 weights: 4 m-tiles x 54 chunks ----------------
// d2w: (128 ci, 512 co, 27 kid). K order kid-major ci-minor (3456 total).
__global__ __launch_bounds__(256)
void k_splitwd2(const float* __restrict__ W, char* __restrict__ Wb)
{
    int g = blockIdx.x*256 + threadIdx.x;   // 4*54*8192 = 1,769,472
    int el   = g & 8191;
    int tile = g >> 13;                      // mG*54 + c
    int mG = tile / 54, c = tile - mG*54;
    int co = el >> 6, kl = el & 63;
    int kg = c*64 + kl;
    int kid = kg >> 7, ci = kg & 127;
    float x = W[((size_t)ci*512 + (mG*128 + co))*27 + kid];
    _Float16 a0, a1, a2; split3(x, a0, a1, a2);
    char* dst = Wb + (size_t)tile*49152 + (co*128 + ((kl*2) ^ ((co&7)<<4)));
    *(_Float16*)(dst)         = a0;
    *(_Float16*)(dst + 16384) = a1;
    *(_Float16*)(dst + 32768) = a2;
}

// ---------------- conv1 MFMA: 128->256, k5, 24^3 -> 20^3 ----------------
__global__ __launch_bounds__(256, 2)
void k_conv1(const float* __restrict__ meshS, const char* __restrict__ Wb,
             const float* __restrict__ bias, _Float16* __restrict__ h1cl)
{
    extern __shared__ char lds[];           // 49152 (A) + 24576 (B) = 73728
    const int tid = threadIdx.x;
    const int l   = tid & 63;
    const int w   = tid >> 6;
    const int wm  = w >> 1, wn = w & 1;
    const int n0  = blockIdx.x * 64;
    const int m   = blockIdx.y;

    const int q   = tid >> 6;
    const int nT  = n0 + (tid & 63);
    const int bB  = nT / 8000;
    const int soT = nT - bB*8000;
    const int xT = soT/400, yT = (soT/20)%20, zT = soT%20;
    const float* bsrc = meshS + ((size_t)(bB*13824 + xT*576 + yT*24 + zT))*128;
    const int nRow = tid & 63;
    const int bw0 = 49152 + nRow*128 + ((q*32)      ^ ((nRow&7)<<4));
    const int bw1 = 49152 + nRow*128 + ((q*32 + 16) ^ ((nRow&7)<<4));

    const int swz = (l & 7) << 4;
    const int qo  = (l >> 4) << 4;
    const int plF = (l & 15)*128 + (qo ^ (swz & 0x30)) + (swz & 0x40);

    f32x4 acc0[4][2], acc1[4][2], acc2[4][2];
    const f32x4 zz = {0.f, 0.f, 0.f, 0.f};
    #pragma unroll
    for (int a = 0; a < 4; ++a)
        #pragma unroll
        for (int b = 0; b < 2; ++b) { acc0[a][b] = zz; acc1[a][b] = zz; acc2[a][b] = zz; }

    for (int c = 0; c < 250; ++c) {
        int kid = c >> 1;
        int kd = kid/25, rr = kid - kd*25, kh = rr/5, kw = rr - kh*5;
        int koff = (kd*576 + kh*24 + kw)*128 + (c & 1)*64;
        const float* src = bsrc + koff + q*16;
        float fv[16];
        *(float4*)&fv[0]  = *(const float4*)(src);
        *(float4*)&fv[4]  = *(const float4*)(src + 4);
        *(float4*)&fv[8]  = *(const float4*)(src + 8);
        *(float4*)&fv[12] = *(const float4*)(src + 12);

        __syncthreads();
        {
            const char* wsrc = (const char*)Wb + ((size_t)(m*250 + c))*49152 + w*12288;
            #pragma unroll
            for (int i = 0; i < 12; ++i)
                gload16(wsrc + i*1024 + l*16, lds + w*12288 + i*1024);
        }
        {
            h8 p0[2], p1[2], p2[2];
            #pragma unroll
            for (int s = 0; s < 2; ++s)
                #pragma unroll
                for (int e = 0; e < 8; ++e) {
                    _Float16 t0, t1, t2; split3(fv[s*8+e], t0, t1, t2);
                    p0[s][e] = t0; p1[s][e] = t1; p2[s][e] = t2;
                }
            *(h8*)(lds + bw0)          = p0[0]; *(h8*)(lds + bw1)          = p0[1];
            *(h8*)(lds + 8192  + bw0)  = p1[0]; *(h8*)(lds + 8192  + bw1)  = p1[1];
            *(h8*)(lds + 16384 + bw0)  = p2[0]; *(h8*)(lds + 16384 + bw1)  = p2[1];
        }
        __syncthreads();

        #pragma unroll
        for (int ks = 0; ks < 2; ++ks) {
            const int kx = ks ? 64 : 0;
            h8 af[3][4], bf[3][2];
            #pragma unroll
            for (int v = 0; v < 3; ++v) {
                #pragma unroll
                for (int mf = 0; mf < 4; ++mf)
                    af[v][mf] = *(const h8*)(lds + v*16384 + (wm*64 + mf*16)*128 + (plF ^ kx));
                #pragma unroll
                for (int nf = 0; nf < 2; ++nf)
                    bf[v][nf] = *(const h8*)(lds + 49152 + v*8192 + (wn*32 + nf*16)*128 + (plF ^ kx));
            }
            #pragma unroll
            for (int mf = 0; mf < 4; ++mf)
                #pragma unroll
                for (int nf = 0; nf < 2; ++nf) {
                    acc0[mf][nf] = __builtin_amdgcn_mfma_f32_16x16x32_f16(af[0][mf], bf[0][nf], acc0[mf][nf], 0,0,0);
                    acc1[mf][nf] = __builtin_amdgcn_mfma_f32_16x16x32_f16(af[0][mf], bf[1][nf], acc1[mf][nf], 0,0,0);
                    acc1[mf][nf] = __builtin_amdgcn_mfma_f32_16x16x32_f16(af[1][mf], bf[0][nf], acc1[mf][nf], 0,0,0);
                    acc2[mf][nf] = __builtin_amdgcn_mfma_f32_16x16x32_f16(af[0][mf], bf[2][nf], acc2[mf][nf], 0,0,0);
                    acc2[mf][nf] = __builtin_amdgcn_mfma_f32_16x16x32_f16(af[1][mf], bf[1][nf], acc2[mf][nf], 0,0,0);
                    acc2[mf][nf] = __builtin_amdgcn_mfma_f32_16x16x32_f16(af[2][mf], bf[0][nf], acc2[mf][nf], 0,0,0);
                }
        }
    }

    const float s1 = 4.8828125e-04f, s2 = 2.384185791015625e-07f;
    #pragma unroll
    for (int mf = 0; mf < 4; ++mf)
        #pragma unroll
        for (int nf = 0; nf < 2; ++nf) {
            f32x4 r = acc0[mf][nf] + s1*acc1[mf][nf] + s2*acc2[mf][nf];
            int co = m*128 + wm*64 + mf*16 + ((l>>4)<<2);
            int n  = n0 + wn*32 + nf*16 + (l&15);
            size_t base = (size_t)n*256 + co;
            h4 v0, v1, v2;
            #pragma unroll
            for (int rr = 0; rr < 4; ++rr) {
                float x = fmaxf(r[rr] + bias[co + rr], 0.f);
                _Float16 t0, t1, t2; split3(x, t0, t1, t2);
                v0[rr] = t0; v1[rr] = t1; v2[rr] = t2;
            }
            *(h4*)(h1cl + base)           = v0;
            *(h4*)(h1cl + 4096000 + base) = v1;
            *(h4*)(h1cl + 8192000 + base) = v2;
        }
}

// ---------------- conv2 MFMA: 256->256, k5, 20^3 -> 16^3, two sequential K-halves ----------------
__global__ __launch_bounds__(256, 2)
void k_conv2(const _Float16* __restrict__ h1cl, const char* __restrict__ Wb,
             const float* __restrict__ bias, float* __restrict__ h2,
             int cBase, int NSt, int accum)
{
    extern __shared__ char lds[];
    const int tid = threadIdx.x;
    const int l   = tid & 63;
    const int w   = tid >> 6;
    const int wm  = w >> 1, wn = w & 1;
    const int n0  = blockIdx.x * 64;
    const int m   = blockIdx.y;

    const _Float16* preP[6];
    #pragma unroll
    for (int i = 0; i < 6; ++i) {
        int g   = w*6144 + i*1024 + l*16;
        int ver = g >> 13;
        int dd  = g & 8191;
        int nl  = dd >> 7;
        int lg  = (dd & 127) ^ ((nl & 7) << 4);
        int klocal = lg >> 1;
        int n = n0 + nl;
        int b2 = n >> 12, so = n & 4095;
        int x = so >> 8, y = (so >> 4) & 15, z = so & 15;
        preP[i] = h1cl + (size_t)ver*4096000
                       + ((size_t)(b2*8000 + x*400 + y*20 + z))*256 + klocal;
    }

    const int swz = (l & 7) << 4;
    const int qo  = (l >> 4) << 4;
    const int plF = (l & 15)*128 + (qo ^ (swz & 0x30)) + (swz & 0x40);

    f32x4 acc0[4][2], acc1[4][2], acc2[4][2];
    const f32x4 zz = {0.f, 0.f, 0.f, 0.f};
    #pragma unroll
    for (int a = 0; a < 4; ++a)
        #pragma unroll
        for (int b = 0; b < 2; ++b) { acc0[a][b] = zz; acc1[a][b] = zz; acc2[a][b] = zz; }

    for (int c = 0; c < NSt; ++c) {
        int cg = cBase + c;
        int kid = cg >> 2;
        int kd = kid/25, rr = kid - kd*25, kh = rr/5, kw = rr - kh*5;
        int koff = (kd*400 + kh*20 + kw)*256 + (cg & 3)*64;

        __syncthreads();
        {
            const char* wsrc = (const char*)Wb + ((size_t)(m*NSt + c))*49152 + w*12288;
            #pragma unroll
            for (int i = 0; i < 12; ++i)
                gload16(wsrc + i*1024 + l*16, lds + w*12288 + i*1024);
            #pragma unroll
            for (int i = 0; i < 6; ++i)
                gload16(preP[i] + koff, lds + 49152 + w*6144 + i*1024);
        }
        __syncthreads();

        #pragma unroll
        for (int ks = 0; ks < 2; ++ks) {
            const int kx = ks ? 64 : 0;
            h8 af[3][4], bf[3][2];
            #pragma unroll
            for (int v = 0; v < 3; ++v) {
                #pragma unroll
                for (int mf = 0; mf < 4; ++mf)
                    af[v][mf] = *(const h8*)(lds + v*16384 + (wm*64 + mf*16)*128 + (plF ^ kx));
                #pragma unroll
                for (int nf = 0; nf < 2; ++nf)
                    bf[v][nf] = *(const h8*)(lds + 49152 + v*8192 + (wn*32 + nf*16)*128 + (plF ^ kx));
            }
            #pragma unroll
            for (int mf = 0; mf < 4; ++mf)
                #pragma unroll
                for (int nf = 0; nf < 2; ++nf) {
                    acc0[mf][nf] = __builtin_amdgcn_mfma_f32_16x16x32_f16(af[0][mf], bf[0][nf], acc0[mf][nf], 0,0,0);
                    acc1[mf][nf] = __builtin_amdgcn_mfma_f32_16x16x32_f16(af[0][mf], bf[1][nf], acc1[mf][nf], 0,0,0);
                    acc1[mf][nf] = __builtin_amdgcn_mfma_f32_16x16x32_f16(af[1][mf], bf[0][nf], acc1[mf][nf], 0,0,0);
                    acc2[mf][nf] = __builtin_amdgcn_mfma_f32_16x16x32_f16(af[0][mf], bf[2][nf], acc2[mf][nf], 0,0,0);
                    acc2[mf][nf] = __builtin_amdgcn_mfma_f32_16x16x32_f16(af[1][mf], bf[1][nf], acc2[mf][nf], 0,0,0);
                    acc2[mf][nf] = __builtin_amdgcn_mfma_f32_16x16x32_f16(af[2][mf], bf[0][nf], acc2[mf][nf], 0,0,0);
                }
        }
    }

    const float s1 = 4.8828125e-04f, s2 = 2.384185791015625e-07f;
    #pragma unroll
    for (int mf = 0; mf < 4; ++mf)
        #pragma unroll
        for (int nf = 0; nf < 2; ++nf) {
            f32x4 r = acc0[mf][nf] + s1*acc1[mf][nf] + s2*acc2[mf][nf];
            int co = m*128 + wm*64 + mf*16 + ((l>>4)<<2);
            int n  = n0 + wn*32 + nf*16 + (l&15);
            int b2 = n >> 12, so = n & 4095;
            #pragma unroll
            for (int rr = 0; rr < 4; ++rr) {
                size_t idx = ((size_t)(b2*256 + co + rr))*4096 + so;
                if (accum) h2[idx] = fmaxf(r[rr] + h2[idx] + bias[co + rr], 0.f);
                else       h2[idx] = r[rr];
            }
        }
}

// ---------------- fp32 implicit-GEMM conv (primary caps only) ----------------
template<int CIN, int KD, int STRIDE, int IND, int OUTD>
__global__ __launch_bounds__(256, 2)
void k_gemm_conv(const float* __restrict__ in, const float* __restrict__ W,
                 float* __restrict__ out)
{
    constexpr int KD2  = KD*KD;
    constexpr int K3   = KD*KD*KD;
    constexpr int IND2 = IND*IND;
    constexpr int IND3 = IND2*IND;
    constexpr int OUT2 = OUTD*OUTD;
    constexpr int OUT3 = OUT2*OUTD;
    constexpr int KTOT = CIN*K3;
    constexpr int NCH  = KTOT/16;

    const int tid  = threadIdx.x;
    const int mIdx = tid >> 4;
    const int nIdx = tid & 15;
    const int n0   = blockIdx.x * 128;
    const int co0  = blockIdx.y * 128;
    const int per  = NCH / (int)gridDim.z;
    const int c0   = blockIdx.z * per;
    const int c1   = c0 + per;

    __shared__ float As[16][132];
    __shared__ float Bs[16][132];

    const int nB    = n0 + (tid & 127);
    const int kHalf = tid >> 7;
    int bB = nB / OUT3;
    int sB = nB - bB*OUT3;
    int xB = sB / OUT2;
    int yB = (sB / OUTD) % OUTD;
    int zB = sB % OUTD;
    const float* inB = in + (size_t)bB*CIN*IND3
                          + (xB*STRIDE)*IND2 + (yB*STRIDE)*IND + (zB*STRIDE);
    const int cB  = tid & 127;
    const int qB  = cB >> 2;
    const int bpos = ((((qB & 1) << 4) | (qB >> 1)) << 2) | (cB & 3);

    const int aCo = tid >> 2;
    const int aKq = (tid & 3) * 4;
    const int qA  = aCo >> 2;
    const int apos = ((((qA & 1) << 4) | (qA >> 1)) << 2) | (aCo & 3);
    const float* Wr0 = W + (size_t)(co0 + aCo)*KTOT + aKq;
    const float* Wr1 = W + (size_t)(co0 + 64 + aCo)*KTOT + aKq;

    float acc[8][8];
    #pragma unroll
    for (int i = 0; i < 8; ++i)
        #pragma unroll
        for (int j = 0; j < 8; ++j) acc[i][j] = 0.f;

    for (int c = c0; c < c1; ++c) {
        const int kb = c*16;
        float4 a0 = *(const float4*)(Wr0 + kb);
        float4 a1 = *(const float4*)(Wr1 + kb);
        float bv[8];
        #pragma unroll
        for (int p = 0; p < 8; ++p) {
            int k  = kb + p*2 + kHalf;
            int ci = k / K3;
            int r  = k - ci*K3;
            int kd = r / KD2;
            int r2 = r - kd*KD2;
            int kh = r2 / KD;
            int kw = r2 - kh*KD;
            bv[p] = inB[ci*IND3 + kd*IND2 + kh*IND + kw];
        }
        __syncthreads();
        As[aKq+0][apos] = a0.x; As[aKq+1][apos] = a0.y;
        As[aKq+2][apos] = a0.z; As[aKq+3][apos] = a0.w;
        As[aKq+0][apos+32] = a1.x; As[aKq+1][apos+32] = a1.y;
        As[aKq+2][apos+32] = a1.z; As[aKq+3][apos+32] = a1.w;
        #pragma unroll
        for (int p = 0; p < 8; ++p) Bs[p*2 + kHalf][bpos] = bv[p];
        __syncthreads();
        #pragma unroll
        for (int kk = 0; kk < 16; ++kk) {
            float af[8], bf[8];
            *(float4*)&af[0] = *(const float4*)&As[kk][mIdx*4];
            *(float4*)&af[4] = *(const float4*)&As[kk][64 + mIdx*4];
            *(float4*)&bf[0] = *(const float4*)&Bs[kk][nIdx*4];
            *(float4*)&bf[4] = *(const float4*)&Bs[kk][64 + nIdx*4];
            #pragma unroll
            for (int i = 0; i < 8; ++i)
                #pragma unroll
                for (int j = 0; j < 8; ++j)
                    acc[i][j] += af[i]*bf[j];
        }
    }

    #pragma unroll
    for (int j = 0; j < 8; ++j) {
        int n = n0 + nIdx*8 + j;
        int b = n / OUT3;
        int s = n - b*OUT3;
        float* o = out + ((size_t)b*256 + co0 + mIdx*8)*OUT3 + s;
        #pragma unroll
        for (int i = 0; i < 8; ++i)
            atomicAdd(o + (size_t)i*OUT3, acc[i][j]);
    }
}

// ---------------- squash primary capsules ----------------
__global__ __launch_bounds__(256)
void k_squash_u(const float* __restrict__ p_buf, const float* __restrict__ pbias,
                float* __restrict__ u)
{
    int g = blockIdx.x*256 + threadIdx.x;      // B*2048 = 4096
    int b = g >> 11;
    int i = g & 2047;
    int cap = i >> 6;
    int s   = i & 63;
    float vals[8];
    float sq = 0.f;
    #pragma unroll
    for (int c = 0; c < 8; ++c) {
        float x = p_buf[((size_t)(b*256) + cap*8 + c)*64 + s] + pbias[cap*8 + c];
        vals[c] = x;
        sq += x*x;
    }
    float scale = (sq / (1.f + sq)) / sqrtf(sq + 1e-8f);
    #pragma unroll
    for (int c = 0; c < 8; ++c) u[(size_t)g*8 + c] = vals[c]*scale;
}

// ---------------- routing ----------------
__global__ __launch_bounds__(256)
void k_route(const float* __restrict__ Wr, const float* __restrict__ u,
             float* __restrict__ s_buf)
{
    int j  = blockIdx.x;
    int i0 = blockIdx.y * 512;
    __shared__ float us[2*512*8];
    for (int idx = threadIdx.x; idx < 8192; idx += 256) {
        int b = idx >> 12;
        us[idx] = u[(size_t)b*16384 + (size_t)i0*8 + (idx & 4095)];
    }
    __syncthreads();
    int tid = threadIdx.x;
    int cc  = tid & 7;
    const float* Wj = Wr + (size_t)j*2048*512 + (size_t)i0*512;
    float a00 = 0.f, a01 = 0.f, a10 = 0.f, a11 = 0.f;
    for (int i = 0; i < 512; ++i) {
        float w0 = Wj[(size_t)i*512 + tid];
        float w1 = Wj[(size_t)i*512 + tid + 256];
        float u0 = us[i*8 + cc];
        float u1 = us[4096 + i*8 + cc];
        a00 += w0*u0; a01 += w1*u0; a10 += w0*u1; a11 += w1*u1;
    }
    __syncthreads();
    float* red = us;
    red[tid] = a00; red[256 + tid] = a01; red[512 + tid] = a10; red[768 + tid] = a11;
    __syncthreads();
    if (tid < 128) {
        int b = tid >> 6, d = tid & 63;
        const float* rb = red + b*512 + (d >> 5)*256 + (d & 31)*8;
        float s = 0.f;
        #pragma unroll
        for (int c2 = 0; c2 < 8; ++c2) s += rb[c2];
        atomicAdd(&s_buf[((size_t)b*50 + j)*64 + d], s * (1.0f/50.0f));
    }
}

// ---------------- squash v ----------------
__global__ __launch_bounds__(64)
void k_squash_v(const float* __restrict__ s_buf, float* __restrict__ v_buf)
{
    int row = blockIdx.x;
    int d   = threadIdx.x;
    float s  = s_buf[row*64 + d];
    float sq = s*s;
    #pragma unroll
    for (int o = 32; o > 0; o >>= 1) sq += __shfl_xor(sq, o);
    float scale = (sq / (1.f + sq)) / sqrtf(sq + 1e-8f);
    v_buf[row*64 + d] = s*scale;
}

// ---------------- dec1 -> fp16x3 channel-last limbs ----------------
// d1cl3 plane: [b][pos1728][ci128], plane stride 442368 elements
__global__ __launch_bounds__(256)
void k_dec1(const float* __restrict__ v, const float* __restrict__ W,
            const float* __restrict__ bias, _Float16* __restrict__ d1cl)
{
    int g  = blockIdx.x*256 + threadIdx.x;  // 442368
    int co = g & 127;
    int t  = g >> 7;
    int o  = t % 1728;
    int b  = t / 1728;
    int ox = o / 144, oy = (o/12) % 12, oz = o % 12;
    int ix = ox/3, ka = ox - 3*ix;
    int iy = oy/3, kb = oy - 3*iy;
    int iz = oz/3, kc = oz - 3*iz;
    int widx = ka*9 + kb*3 + kc;
    int sidx = ix*16 + iy*4 + iz;
    float s = 0.f;
    for (int ci = 0; ci < 50; ++ci)
        s += v[((size_t)b*50 + ci)*64 + sidx] * W[((size_t)ci*128 + co)*27 + widx];
    float x = fmaxf(s + bias[co], 0.f);
    _Float16 a0, a1, a2; split3(x, a0, a1, a2);
    size_t base = (size_t)(b*1728 + o)*128 + co;
    d1cl[base]          = a0;
    d1cl[base + 442368] = a1;
    d1cl[base + 884736] = a2;
}

// ---------------- dec2 MFMA: ConvTranspose3d(128->512, k3, s2, p1, op1), per co-half ----------------
// d1cl3 limbs as B, Wb2 image as A. Block 128M x 64N, BK=64, 54 steps.
// out: (B*N3, 256) fp32 half-slab.
__global__ __launch_bounds__(256, 2)
void k_dec2m(const _Float16* __restrict__ d1cl, const char* __restrict__ Wb,
             const float* __restrict__ bias, float* __restrict__ out, int coBase)
{
    extern __shared__ char lds[];           // 49152 + 24576
    const int tid = threadIdx.x;
    const int l   = tid & 63;
    const int w   = tid >> 6;
    const int wm  = w >> 1, wn = w & 1;
    const int n0  = blockIdx.x * 64;        // over 27648
    const int m   = blockIdx.y;             // 0..1 within half
    const int mG  = (coBase >> 7) + m;      // global m-tile 0..3

    // B staging thread coords: n = tid&63, ci-quarter q
    const int q  = tid >> 6;
    const int nT = n0 + (tid & 63);
    const int bB = nT / 13824;
    const int so = nT - bB*13824;
    const int ox = so/576, oy = (so/24)%24, oz = so%24;

    // per-axis transposed-conv taps (kd/kh/kw in 0..2): t = o + 1 - k
    int xo0, xo1, xo2, yo0, yo1, yo2, zo0, zo1, zo2;
    bool okx0, okx1, okx2, oky0, oky1, oky2, okz0, okz1, okz2;
    {
        int t;
        t = ox+1; okx0 = ((t&1)==0) && ((unsigned)t<24u); xo0 = okx0 ? (t>>1)*144 : 0;
        t = ox;   okx1 = ((t&1)==0) && ((unsigned)t<24u); xo1 = okx1 ? (t>>1)*144 : 0;
        t = ox-1; okx2 = ((t&1)==0) && ((unsigned)t<24u); xo2 = okx2 ? (t>>1)*144 : 0;
        t = oy+1; oky0 = ((t&1)==0) && ((unsigned)t<24u); yo0 = oky0 ? (t>>1)*12  : 0;
        t = oy;   oky1 = ((t&1)==0) && ((unsigned)t<24u); yo1 = oky1 ? (t>>1)*12  : 0;
        t = oy-1; oky2 = ((t&1)==0) && ((unsigned)t<24u); yo2 = oky2 ? (t>>1)*12  : 0;
        t = oz+1; okz0 = ((t&1)==0) && ((unsigned)t<24u); zo0 = okz0 ? (t>>1)     : 0;
        t = oz;   okz1 = ((t&1)==0) && ((unsigned)t<24u); zo1 = okz1 ? (t>>1)     : 0;
        t = oz-1; okz2 = ((t&1)==0) && ((unsigned)t<24u); zo2 = okz2 ? (t>>1)     : 0;
    }
    const int posBase = bB*1728;
    const int nRow = tid & 63;
    const int bw0 = 49152 + nRow*128 + ((q*32)      ^ ((nRow&7)<<4));
    const int bw1 = 49152 + nRow*128 + ((q*32 + 16) ^ ((nRow&7)<<4));

    const int swz = (l & 7) << 4;
    const int qo  = (l >> 4) << 4;
    const int plF = (l & 15)*128 + (qo ^ (swz & 0x30)) + (swz & 0x40);

    f32x4 acc0[4][2], acc1[4][2], acc2[4][2];
    const f32x4 zz = {0.f, 0.f, 0.f, 0.f};
    #pragma unroll
    for (int a = 0; a < 4; ++a)
        #pragma unroll
        for (int b = 0; b < 2; ++b) { acc0[a][b] = zz; acc1[a][b] = zz; acc2[a][b] = zz; }

    const h8 z8 = {};
    for (int c = 0; c < 54; ++c) {
        int kid = c >> 1;
        int kd = kid/9; int rm = kid - kd*9; int kh = rm/3; int kw = rm - kh*3;
        int xo = (kd==0) ? xo0 : ((kd==1) ? xo1 : xo2);
        int yo = (kh==0) ? yo0 : ((kh==1) ? yo1 : yo2);
        int zo = (kw==0) ? zo0 : ((kw==1) ? zo1 : zo2);
        bool okx = (kd==0) ? okx0 : ((kd==1) ? okx1 : okx2);
        bool oky = (kh==0) ? oky0 : ((kh==1) ? oky1 : oky2);
        bool okz = (kw==0) ? okz0 : ((kw==1) ? okz1 : okz2);
        bool ok = okx && oky && okz;
        const _Float16* src = d1cl + (size_t)(posBase + xo + yo + zo)*128
                                   + (c & 1)*64 + q*16;
        h8 b0a = *(const h8*)(src);
        h8 b0b = *(const h8*)(src + 8);
        h8 b1a = *(const h8*)(src + 442368);
        h8 b1b = *(const h8*)(src + 442368 + 8);
        h8 b2a = *(const h8*)(src + 884736);
        h8 b2b = *(const h8*)(src + 884736 + 8);

        __syncthreads();
        {
            const char* wsrc = (const char*)Wb + ((size_t)(mG*54 + c))*49152 + w*12288;
            #pragma unroll
            for (int i = 0; i < 12; ++i)
                gload16(wsrc + i*1024 + l*16, lds + w*12288 + i*1024);
        }
        *(h8*)(lds + bw0)          = ok ? b0a : z8;
        *(h8*)(lds + bw1)          = ok ? b0b : z8;
        *(h8*)(lds + 8192  + bw0)  = ok ? b1a : z8;
        *(h8*)(lds + 8192  + bw1)  = ok ? b1b : z8;
        *(h8*)(lds + 16384 + bw0)  = ok ? b2a : z8;
        *(h8*)(lds + 16384 + bw1)  = ok ? b2b : z8;
        __syncthreads();

        #pragma unroll
        for (int ks = 0; ks < 2; ++ks) {
            const int kx = ks ? 64 : 0;
            h8 af[3][4], bf[3][2];
            #pragma unroll
            for (int v = 0; v < 3; ++v) {
                #pragma unroll
                for (int mf = 0; mf < 4; ++mf)
                    af[v][mf] = *(const h8*)(lds + v*16384 + (wm*64 + mf*16)*128 + (plF ^ kx));
                #pragma unroll
                for (int nf = 0; nf < 2; ++nf)
                    bf[v][nf] = *(const h8*)(lds + 49152 + v*8192 + (wn*32 + nf*16)*128 + (plF ^ kx));
            }
            #pragma unroll
            for (int mf = 0; mf < 4; ++mf)
                #pragma unroll
                for (int nf = 0; nf < 2; ++nf) {
                    acc0[mf][nf] = __builtin_amdgcn_mfma_f32_16x16x32_f16(af[0][mf], bf[0][nf], acc0[mf][nf], 0,0,0);
                    acc1[mf][nf] = __builtin_amdgcn_mfma_f32_16x16x32_f16(af[0][mf], bf[1][nf], acc1[mf][nf], 0,0,0);
                    acc1[mf][nf] = __builtin_amdgcn_mfma_f32_16x16x32_f16(af[1][mf], bf[0][nf], acc1[mf][nf], 0,0,0);
                    acc2[mf][nf] = __builtin_amdgcn_mfma_f32_16x16x32_f16(af[0][mf], bf[2][nf], acc2[mf][nf], 0,0,0);
                    acc2[mf][nf] = __builtin_amdgcn_mfma_f32_16x16x32_f16(af[1][mf], bf[1][nf], acc2[mf][nf], 0,0,0);
                    acc2[mf][nf] = __builtin_amdgcn_mfma_f32_16x16x32_f16(af[2][mf], bf[0][nf], acc2[mf][nf], 0,0,0);
                }
        }
    }

    const float s1 = 4.8828125e-04f, s2 = 2.384185791015625e-07f;
    #pragma unroll
    for (int mf = 0; mf < 4; ++mf)
        #pragma unroll
        for (int nf = 0; nf < 2; ++nf) {
            f32x4 r = acc0[mf][nf] + s1*acc1[mf][nf] + s2*acc2[mf][nf];
            int coL = m*128 + wm*64 + mf*16 + ((l>>4)<<2);   // 0..255 within half
            int coG = coBase + coL;
            int n   = n0 + wn*32 + nf*16 + (l&15);
            float4 v;
            v.x = fmaxf(r[0] + bias[coG + 0], 0.f);
            v.y = fmaxf(r[1] + bias[coG + 1], 0.f);
            v.z = fmaxf(r[2] + bias[coG + 2], 0.f);
            v.w = fmaxf(r[3] + bias[coG + 3], 0.f);
            *(float4*)(out + (size_t)n*256 + coL) = v;
        }
}

// ---------------- final gather (per co-half) ----------------
__global__ __launch_bounds__(256)
void k_gather(const float* __restrict__ d2h, const int* __restrict__ vid,
              float* __restrict__ out, int colOff)
{
    int g  = blockIdx.x*256 + threadIdx.x;   // B*P*64 float4 units
    int qq = g & 63;
    int bp = g >> 6;
    int v  = vid[bp];
    int b  = bp >> 13;
    float4 val = *(const float4*)&d2h[((size_t)(b*N3 + v))*256 + qq*4];
    *(float4*)&out[(size_t)bp*512 + colOff + qq*4] = val;
}

extern "C" void kernel_launch(void* const* d_in, const int* in_sizes, int n_in,
                              void* d_out, int out_size, void* d_ws, size_t ws_size,
                              hipStream_t stream)
{
    (void)in_sizes; (void)n_in; (void)out_size; (void)ws_size;
    const float* pcl  = (const float*)d_in[0];
    const float* feat = (const float*)d_in[1];
    const float* c1w  = (const float*)d_in[3];
    const float* c1b  = (const float*)d_in[4];
    const float* c2w  = (const float*)d_in[5];
    const float* c2b  = (const float*)d_in[6];
    const float* pw   = (const float*)d_in[7];
    const float* pb   = (const float*)d_in[8];
    const float* rw   = (const float*)d_in[9];
    const float* d1w  = (const float*)d_in[10];
    const float* d1b_ = (const float*)d_in[11];
    const float* d2w  = (const float*)d_in[12];
    const float* d2b  = (const float*)d_in[13];

    char* ws = (char*)d_ws;
    char*      Wb    = ws + WB_OFF;
    _Float16*  h1cl  = (_Float16*)(ws + H1CL_OFF);
    float*     meshS = (float*)(ws + MESHS_OFF);
    float*     d2h   = (float*)(ws + D2H_OFF);
    char*      Wb2   = ws + WB2_OFF;
    _Float16*  d1cl  = (_Float16*)(ws + D1CL_OFF);
    float*     h2    = (float*)(ws + H2_OFF);
    int*       vid   = (int*)(ws + VID_OFF);
    float*     p_buf = (float*)(ws + PBUF_OFF);
    float*     u_buf = (float*)(ws + UBUF_OFF);
    float*     s_buf = (float*)(ws + SBUF_OFF);
    float*     v_buf = (float*)(ws + VBUF_OFF);

    k_vid<<<dim3(B_), dim3(256), 0, stream>>>(pcl, vid);

    hipMemsetAsync(meshS, 0, 14155776, stream);
    k_scatter<<<dim3(8192), dim3(256), 0, stream>>>(feat, vid, meshS);

    // conv1
    k_splitw1<<<dim3(16000), dim3(256), 0, stream>>>(c1w, Wb);
    k_conv1<<<dim3(250, 2), dim3(256), 73728, stream>>>(meshS, Wb, c1b, h1cl);

    // conv2 in two K-halves
    k_splitw2<<<dim3(248*64), dim3(256), 0, stream>>>(c2w, Wb, 0, 248);
    k_conv2<<<dim3(128, 2), dim3(256), 73728, stream>>>(h1cl, Wb, c2b, h2, 0, 248, 0);
    k_splitw2<<<dim3(252*64), dim3(256), 0, stream>>>(c2w, Wb, 248, 252);
    k_conv2<<<dim3(128, 2), dim3(256), 73728, stream>>>(h1cl, Wb, c2b, h2, 248, 252, 1);

    // dec2 weight pre-split (region overlaps h1cl -> must run after conv2)
    k_splitwd2<<<dim3(6912), dim3(256), 0, stream>>>(d2w, Wb2);

    // primary caps: fp32 path, splitk 216
    hipMemsetAsync(p_buf, 0, 131072, stream);
    k_gemm_conv<256,9,2,16,4><<<dim3(1, 2, 216), dim3(256), 0, stream>>>(h2, pw, p_buf);
    k_squash_u<<<dim3(16), dim3(256), 0, stream>>>(p_buf, pb, u_buf);

    hipMemsetAsync(s_buf, 0, 25600, stream);
    k_route<<<dim3(50, 4), dim3(256), 0, stream>>>(rw, u_buf, s_buf);
    k_squash_v<<<dim3(100), dim3(64), 0, stream>>>(s_buf, v_buf);

    k_dec1<<<dim3(1728), dim3(256), 0, stream>>>(v_buf, d1w, d1b_, d1cl);

    k_dec2m<<<dim3(432, 2), dim3(256), 73728, stream>>>(d1cl, Wb2, d2b, d2h, 0);
    k_gather<<<dim3(4096), dim3(256), 0, stream>>>(d2h, vid, (float*)d_out, 0);
    k_dec2m<<<dim3(432, 2), dim3(256), 73728, stream>>>(d1cl, Wb2, d2b, d2h, 256);
    k_gather<<<dim3(4096), dim3(256), 0, stream>>>(d2h, vid, (float*)d_out, 256);
}

// Round 6
// 2152.973 us; speedup vs baseline: 4.5509x; 1.3089x over previous
//
#include <hip/hip_runtime.h>
#include <cstdint>
#include <cstddef>

typedef _Float16 h8 __attribute__((ext_vector_type(8)));
typedef _Float16 h4 __attribute__((ext_vector_type(4)));
typedef float    f32x4 __attribute__((ext_vector_type(4)));

#define B_   2
#define P_   8192
#define NVOX 24
#define N3   13824

// ---- workspace layout (bytes). Peak 63,883,264 (same tail as r4/r5). ----
// Phase A (scatter/conv): WB [0,16,515,072) ; h1cl [16,515,072, 32,899,072)
//                         meshS [32,899,072, 47,054,848)
// Phase B (conv2/prim):   h2 [32,899,072, 41,287,680)  (meshS dead)
// Phase C (dec):          Wb2 [0, 7,077,888) ; d2h [7,077,888, 35,389,440)
//                         d1cl [41,287,680, 43,057,152)
#define WB_OFF    0ull
#define H1CL_OFF  16515072ull
#define MESHS_OFF 32899072ull
#define H2_OFF    32899072ull
#define WB2_OFF   0ull
#define D2H_OFF   7077888ull
#define D1CL_OFF  41287680ull
#define VID_OFF   63504384ull
#define PBUF_OFF  63569920ull
#define UBUF_OFF  63700992ull
#define SBUF_OFF  63832064ull
#define VBUF_OFF  63857664ull

// ---------------- helpers ----------------
__device__ inline void split2(float x, _Float16& a0, _Float16& a1)
{
    a0 = (_Float16)x;
    float r = x - (float)a0;
    a1 = (_Float16)(r * 2048.0f);
}

__device__ inline void gload16(const void* g, void* l)
{
    __builtin_amdgcn_global_load_lds(
        (const __attribute__((address_space(1))) char*)g,
        (__attribute__((address_space(3))) char*)l, 16, 0, 0);
}

// ---------------- voxel ids ----------------
__global__ __launch_bounds__(256)
void k_vid(const float* __restrict__ pcl, int* __restrict__ vid)
{
    int b = blockIdx.x;
    const float* pb = pcl + (size_t)b * P_ * 3;
    float mn[3] = {3e38f, 3e38f, 3e38f};
    float mx[3] = {-3e38f, -3e38f, -3e38f};
    for (int p = threadIdx.x; p < P_; p += 256) {
        #pragma unroll
        for (int d = 0; d < 3; ++d) {
            float v = pb[p*3 + d];
            mn[d] = fminf(mn[d], v);
            mx[d] = fmaxf(mx[d], v);
        }
    }
    __shared__ float red[6][256];
    #pragma unroll
    for (int d = 0; d < 3; ++d) { red[d][threadIdx.x] = mn[d]; red[3+d][threadIdx.x] = mx[d]; }
    __syncthreads();
    for (int s = 128; s > 0; s >>= 1) {
        if (threadIdx.x < (unsigned)s) {
            #pragma unroll
            for (int d = 0; d < 3; ++d) {
                red[d][threadIdx.x]   = fminf(red[d][threadIdx.x],   red[d][threadIdx.x + s]);
                red[3+d][threadIdx.x] = fmaxf(red[3+d][threadIdx.x], red[3+d][threadIdx.x + s]);
            }
        }
        __syncthreads();
    }
    float mn0 = red[0][0], mn1 = red[1][0], mn2 = red[2][0];
    float dd0 = red[3][0] - mn0 + 1e-9f;
    float dd1 = red[4][0] - mn1 + 1e-9f;
    float dd2 = red[5][0] - mn2 + 1e-9f;
    for (int p = threadIdx.x; p < P_; p += 256) {
        float fx = (pb[p*3+0] - mn0) / dd0 * 24.0f;
        float fy = (pb[p*3+1] - mn1) / dd1 * 24.0f;
        float fz = (pb[p*3+2] - mn2) / dd2 * 24.0f;
        int ix = (int)floorf(fx); ix = ix < 0 ? 0 : (ix > 23 ? 23 : ix);
        int iy = (int)floorf(fy); iy = iy < 0 ? 0 : (iy > 23 ? 23 : iy);
        int iz = (int)floorf(fz); iz = iz < 0 ? 0 : (iz > 23 ? 23 : iz);
        vid[b*P_ + p] = ix*576 + iy*24 + iz;
    }
}

// ---------------- scatter-add point features -> meshS (B, N3, 128) ----------------
__global__ __launch_bounds__(256)
void k_scatter(const float* __restrict__ feat, const int* __restrict__ vid,
               float* __restrict__ meshS)
{
    int g = blockIdx.x*256 + threadIdx.x;      // B*P*C = 2,097,152
    int c  = g & 127;
    int bp = g >> 7;
    int v  = vid[bp];
    int b  = bp >> 13;
    atomicAdd(&meshS[((size_t)b*N3 + v)*128 + c], feat[g]);
}

// ---------------- pre-split conv1 weights into blocked swizzled fp16x2 image ----------------
// Wb tile (m,c): 32768 B = 2 planes x [128 co][64 k] rows of 128 B, in-row byte ^ ((co&7)<<4)
__global__ __launch_bounds__(256)
void k_splitw1(const float* __restrict__ W, char* __restrict__ Wb)
{
    int g = blockIdx.x*256 + threadIdx.x;   // 4,096,000
    int el   = g & 8191;
    int tile = g >> 13;                      // m*250 + c
    int m = tile / 250, c = tile - m*250;
    int co = el >> 6, kl = el & 63;
    int kg = c*64 + kl;                      // K order: kid-major, ci-minor
    int kid = kg >> 7, ci = kg & 127;
    float x = W[((size_t)((m*128 + co)*128 + ci))*125 + kid];
    _Float16 a0, a1; split2(x, a0, a1);
    char* dst = Wb + (size_t)tile*32768 + (co*128 + ((kl*2) ^ ((co&7)<<4)));
    *(_Float16*)(dst)         = a0;
    *(_Float16*)(dst + 16384) = a1;
}

// ---------------- pre-split conv2 weights (half-K at a time) ----------------
__global__ __launch_bounds__(256)
void k_splitw2(const float* __restrict__ W, char* __restrict__ Wb, int cBase, int NC)
{
    int g = blockIdx.x*256 + threadIdx.x;   // 2*NC*8192
    int el   = g & 8191;
    int tile = g >> 13;                      // m*NC + cl
    int m = tile / NC, cl = tile - m*NC;
    int c = cBase + cl;
    int co = el >> 6, kl = el & 63;
    int kg = c*64 + kl;
    int kid = kg >> 8, ci = kg & 255;
    float x = W[((size_t)((m*128 + co)*256 + ci))*125 + kid];
    _Float16 a0, a1; split2(x, a0, a1);
    char* dst = Wb + (size_t)tile*32768 + (co*128 + ((kl*2) ^ ((co&7)<<4)));
    *(_Float16*)(dst)         = a0;
    *(_Float16*)(dst + 16384) = a1;
}

// ---------------- pre-split dec2 weights: 4 m-tiles x 54 chunks ----------------
__global__ __launch_bounds__(256)
void k_splitwd2(const float* __restrict__ W, char* __restrict__ Wb)
{
    int g = blockIdx.x*256 + threadIdx.x;   // 4*54*8192 = 1,769,472
    int el   = g & 8191;
    int tile = g >> 13;                      // mG*54 + c
    int mG = tile / 54, c = tile - mG*54;
    int co = el >> 6, kl = el & 63;
    int kg = c*64 + kl;
    int kid = kg >> 7, ci = kg & 127;
    float x = W[((size_t)ci*512 + (mG*128 + co))*27 + kid];
    _Float16 a0, a1; split2(x, a0, a1);
    char* dst = Wb + (size_t)tile*32768 + (co*128 + ((kl*2) ^ ((co&7)<<4)));
    *(_Float16*)(dst)         = a0;
    *(_Float16*)(dst + 16384) = a1;
}

// ---------------- conv1 MFMA: 128->256, k5, 24^3 -> 20^3 (2-limb) ----------------
// LDS: A 2x16384 = 32768 ; B 2x8192 = 16384 ; total 49152 -> 3 blocks/CU
__global__ __launch_bounds__(256, 3)
void k_conv1(const float* __restrict__ meshS, const char* __restrict__ Wb,
             const float* __restrict__ bias, _Float16* __restrict__ h1cl)
{
    extern __shared__ char lds[];
    const int tid = threadIdx.x;
    const int l   = tid & 63;
    const int w   = tid >> 6;
    const int wm  = w >> 1, wn = w & 1;
    const int n0  = blockIdx.x * 64;
    const int m   = blockIdx.y;

    const int q   = tid >> 6;
    const int nT  = n0 + (tid & 63);
    const int bB  = nT / 8000;
    const int soT = nT - bB*8000;
    const int xT = soT/400, yT = (soT/20)%20, zT = soT%20;
    const float* bsrc = meshS + ((size_t)(bB*13824 + xT*576 + yT*24 + zT))*128;
    const int nRow = tid & 63;
    const int bw0 = 32768 + nRow*128 + ((q*32)      ^ ((nRow&7)<<4));
    const int bw1 = 32768 + nRow*128 + ((q*32 + 16) ^ ((nRow&7)<<4));

    const int swz = (l & 7) << 4;
    const int qo  = (l >> 4) << 4;
    const int plF = (l & 15)*128 + (qo ^ (swz & 0x30)) + (swz & 0x40);

    f32x4 acc0[4][2], acc1[4][2];
    const f32x4 zz = {0.f, 0.f, 0.f, 0.f};
    #pragma unroll
    for (int a = 0; a < 4; ++a)
        #pragma unroll
        for (int b = 0; b < 2; ++b) { acc0[a][b] = zz; acc1[a][b] = zz; }

    for (int c = 0; c < 250; ++c) {
        int kid = c >> 1;
        int kd = kid/25, rr = kid - kd*25, kh = rr/5, kw = rr - kh*5;
        int koff = (kd*576 + kh*24 + kw)*128 + (c & 1)*64;
        const float* src = bsrc + koff + q*16;
        float fv[16];
        *(float4*)&fv[0]  = *(const float4*)(src);
        *(float4*)&fv[4]  = *(const float4*)(src + 4);
        *(float4*)&fv[8]  = *(const float4*)(src + 8);
        *(float4*)&fv[12] = *(const float4*)(src + 12);

        __syncthreads();
        {
            const char* wsrc = (const char*)Wb + ((size_t)(m*250 + c))*32768 + w*8192;
            #pragma unroll
            for (int i = 0; i < 8; ++i)
                gload16(wsrc + i*1024 + l*16, lds + w*8192 + i*1024);
        }
        {
            h8 p0[2], p1[2];
            #pragma unroll
            for (int s = 0; s < 2; ++s)
                #pragma unroll
                for (int e = 0; e < 8; ++e) {
                    _Float16 t0, t1; split2(fv[s*8+e], t0, t1);
                    p0[s][e] = t0; p1[s][e] = t1;
                }
            *(h8*)(lds + bw0)         = p0[0]; *(h8*)(lds + bw1)         = p0[1];
            *(h8*)(lds + 8192 + bw0)  = p1[0]; *(h8*)(lds + 8192 + bw1)  = p1[1];
        }
        __syncthreads();

        #pragma unroll
        for (int ks = 0; ks < 2; ++ks) {
            const int kx = ks ? 64 : 0;
            h8 af[2][4], bf[2][2];
            #pragma unroll
            for (int v = 0; v < 2; ++v) {
                #pragma unroll
                for (int mf = 0; mf < 4; ++mf)
                    af[v][mf] = *(const h8*)(lds + v*16384 + (wm*64 + mf*16)*128 + (plF ^ kx));
                #pragma unroll
                for (int nf = 0; nf < 2; ++nf)
                    bf[v][nf] = *(const h8*)(lds + 32768 + v*8192 + (wn*32 + nf*16)*128 + (plF ^ kx));
            }
            #pragma unroll
            for (int mf = 0; mf < 4; ++mf)
                #pragma unroll
                for (int nf = 0; nf < 2; ++nf) {
                    acc0[mf][nf] = __builtin_amdgcn_mfma_f32_16x16x32_f16(af[0][mf], bf[0][nf], acc0[mf][nf], 0,0,0);
                    acc1[mf][nf] = __builtin_amdgcn_mfma_f32_16x16x32_f16(af[0][mf], bf[1][nf], acc1[mf][nf], 0,0,0);
                    acc1[mf][nf] = __builtin_amdgcn_mfma_f32_16x16x32_f16(af[1][mf], bf[0][nf], acc1[mf][nf], 0,0,0);
                }
        }
    }

    const float s1 = 4.8828125e-04f;
    #pragma unroll
    for (int mf = 0; mf < 4; ++mf)
        #pragma unroll
        for (int nf = 0; nf < 2; ++nf) {
            f32x4 r = acc0[mf][nf] + s1*acc1[mf][nf];
            int co = m*128 + wm*64 + mf*16 + ((l>>4)<<2);
            int n  = n0 + wn*32 + nf*16 + (l&15);
            size_t base = (size_t)n*256 + co;
            h4 v0, v1;
            #pragma unroll
            for (int rr = 0; rr < 4; ++rr) {
                float x = fmaxf(r[rr] + bias[co + rr], 0.f);
                _Float16 t0, t1; split2(x, t0, t1);
                v0[rr] = t0; v1[rr] = t1;
            }
            *(h4*)(h1cl + base)           = v0;
            *(h4*)(h1cl + 4096000 + base) = v1;
        }
}

// ---------------- conv2 MFMA: 256->256, k5, 20^3 -> 16^3, two sequential K-halves ----------------
__global__ __launch_bounds__(256, 3)
void k_conv2(const _Float16* __restrict__ h1cl, const char* __restrict__ Wb,
             const float* __restrict__ bias, float* __restrict__ h2,
             int cBase, int NSt, int accum)
{
    extern __shared__ char lds[];
    const int tid = threadIdx.x;
    const int l   = tid & 63;
    const int w   = tid >> 6;
    const int wm  = w >> 1, wn = w & 1;
    const int n0  = blockIdx.x * 64;
    const int m   = blockIdx.y;

    // B gload sources (4/wave), inverse-swizzled per-lane addresses
    const _Float16* preP[4];
    #pragma unroll
    for (int i = 0; i < 4; ++i) {
        int g   = w*4096 + i*1024 + l*16;
        int ver = g >> 13;
        int dd  = g & 8191;
        int nl  = dd >> 7;
        int lg  = (dd & 127) ^ ((nl & 7) << 4);
        int klocal = lg >> 1;
        int n = n0 + nl;
        int b2 = n >> 12, so = n & 4095;
        int x = so >> 8, y = (so >> 4) & 15, z = so & 15;
        preP[i] = h1cl + (size_t)ver*4096000
                       + ((size_t)(b2*8000 + x*400 + y*20 + z))*256 + klocal;
    }

    const int swz = (l & 7) << 4;
    const int qo  = (l >> 4) << 4;
    const int plF = (l & 15)*128 + (qo ^ (swz & 0x30)) + (swz & 0x40);

    f32x4 acc0[4][2], acc1[4][2];
    const f32x4 zz = {0.f, 0.f, 0.f, 0.f};
    #pragma unroll
    for (int a = 0; a < 4; ++a)
        #pragma unroll
        for (int b = 0; b < 2; ++b) { acc0[a][b] = zz; acc1[a][b] = zz; }

    for (int c = 0; c < NSt; ++c) {
        int cg = cBase + c;
        int kid = cg >> 2;
        int kd = kid/25, rr = kid - kd*25, kh = rr/5, kw = rr - kh*5;
        int koff = (kd*400 + kh*20 + kw)*256 + (cg & 3)*64;

        __syncthreads();
        {
            const char* wsrc = (const char*)Wb + ((size_t)(m*NSt + c))*32768 + w*8192;
            #pragma unroll
            for (int i = 0; i < 8; ++i)
                gload16(wsrc + i*1024 + l*16, lds + w*8192 + i*1024);
            #pragma unroll
            for (int i = 0; i < 4; ++i)
                gload16(preP[i] + koff, lds + 32768 + w*4096 + i*1024);
        }
        __syncthreads();

        #pragma unroll
        for (int ks = 0; ks < 2; ++ks) {
            const int kx = ks ? 64 : 0;
            h8 af[2][4], bf[2][2];
            #pragma unroll
            for (int v = 0; v < 2; ++v) {
                #pragma unroll
                for (int mf = 0; mf < 4; ++mf)
                    af[v][mf] = *(const h8*)(lds + v*16384 + (wm*64 + mf*16)*128 + (plF ^ kx));
                #pragma unroll
                for (int nf = 0; nf < 2; ++nf)
                    bf[v][nf] = *(const h8*)(lds + 32768 + v*8192 + (wn*32 + nf*16)*128 + (plF ^ kx));
            }
            #pragma unroll
            for (int mf = 0; mf < 4; ++mf)
                #pragma unroll
                for (int nf = 0; nf < 2; ++nf) {
                    acc0[mf][nf] = __builtin_amdgcn_mfma_f32_16x16x32_f16(af[0][mf], bf[0][nf], acc0[mf][nf], 0,0,0);
                    acc1[mf][nf] = __builtin_amdgcn_mfma_f32_16x16x32_f16(af[0][mf], bf[1][nf], acc1[mf][nf], 0,0,0);
                    acc1[mf][nf] = __builtin_amdgcn_mfma_f32_16x16x32_f16(af[1][mf], bf[0][nf], acc1[mf][nf], 0,0,0);
                }
        }
    }

    const float s1 = 4.8828125e-04f;
    #pragma unroll
    for (int mf = 0; mf < 4; ++mf)
        #pragma unroll
        for (int nf = 0; nf < 2; ++nf) {
            f32x4 r = acc0[mf][nf] + s1*acc1[mf][nf];
            int co = m*128 + wm*64 + mf*16 + ((l>>4)<<2);
            int n  = n0 + wn*32 + nf*16 + (l&15);
            int b2 = n >> 12, so = n & 4095;
            #pragma unroll
            for (int rr = 0; rr < 4; ++rr) {
                size_t idx = ((size_t)(b2*256 + co + rr))*4096 + so;
                if (accum) h2[idx] = fmaxf(r[rr] + h2[idx] + bias[co + rr], 0.f);
                else       h2[idx] = r[rr];
            }
        }
}

// ---------------- fp32 implicit-GEMM conv (primary caps only) ----------------
template<int CIN, int KD, int STRIDE, int IND, int OUTD>
__global__ __launch_bounds__(256, 2)
void k_gemm_conv(const float* __restrict__ in, const float* __restrict__ W,
                 float* __restrict__ out)
{
    constexpr int KD2  = KD*KD;
    constexpr int K3   = KD*KD*KD;
    constexpr int IND2 = IND*IND;
    constexpr int IND3 = IND2*IND;
    constexpr int OUT2 = OUTD*OUTD;
    constexpr int OUT3 = OUT2*OUTD;
    constexpr int KTOT = CIN*K3;
    constexpr int NCH  = KTOT/16;

    const int tid  = threadIdx.x;
    const int mIdx = tid >> 4;
    const int nIdx = tid & 15;
    const int n0   = blockIdx.x * 128;
    const int co0  = blockIdx.y * 128;
    const int per  = NCH / (int)gridDim.z;
    const int c0   = blockIdx.z * per;
    const int c1   = c0 + per;

    __shared__ float As[16][132];
    __shared__ float Bs[16][132];

    const int nB    = n0 + (tid & 127);
    const int kHalf = tid >> 7;
    int bB = nB / OUT3;
    int sB = nB - bB*OUT3;
    int xB = sB / OUT2;
    int yB = (sB / OUTD) % OUTD;
    int zB = sB % OUTD;
    const float* inB = in + (size_t)bB*CIN*IND3
                          + (xB*STRIDE)*IND2 + (yB*STRIDE)*IND + (zB*STRIDE);
    const int cB  = tid & 127;
    const int qB  = cB >> 2;
    const int bpos = ((((qB & 1) << 4) | (qB >> 1)) << 2) | (cB & 3);

    const int aCo = tid >> 2;
    const int aKq = (tid & 3) * 4;
    const int qA  = aCo >> 2;
    const int apos = ((((qA & 1) << 4) | (qA >> 1)) << 2) | (aCo & 3);
    const float* Wr0 = W + (size_t)(co0 + aCo)*KTOT + aKq;
    const float* Wr1 = W + (size_t)(co0 + 64 + aCo)*KTOT + aKq;

    float acc[8][8];
    #pragma unroll
    for (int i = 0; i < 8; ++i)
        #pragma unroll
        for (int j = 0; j < 8; ++j) acc[i][j] = 0.f;

    for (int c = c0; c < c1; ++c) {
        const int kb = c*16;
        float4 a0 = *(const float4*)(Wr0 + kb);
        float4 a1 = *(const float4*)(Wr1 + kb);
        float bv[8];
        #pragma unroll
        for (int p = 0; p < 8; ++p) {
            int k  = kb + p*2 + kHalf;
            int ci = k / K3;
            int r  = k - ci*K3;
            int kd = r / KD2;
            int r2 = r - kd*KD2;
            int kh = r2 / KD;
            int kw = r2 - kh*KD;
            bv[p] = inB[ci*IND3 + kd*IND2 + kh*IND + kw];
        }
        __syncthreads();
        As[aKq+0][apos] = a0.x; As[aKq+1][apos] = a0.y;
        As[aKq+2][apos] = a0.z; As[aKq+3][apos] = a0.w;
        As[aKq+0][apos+32] = a1.x; As[aKq+1][apos+32] = a1.y;
        As[aKq+2][apos+32] = a1.z; As[aKq+3][apos+32] = a1.w;
        #pragma unroll
        for (int p = 0; p < 8; ++p) Bs[p*2 + kHalf][bpos] = bv[p];
        __syncthreads();
        #pragma unroll
        for (int kk = 0; kk < 16; ++kk) {
            float af[8], bf[8];
            *(float4*)&af[0] = *(const float4*)&As[kk][mIdx*4];
            *(float4*)&af[4] = *(const float4*)&As[kk][64 + mIdx*4];
            *(float4*)&bf[0] = *(const float4*)&Bs[kk][nIdx*4];
            *(float4*)&bf[4] = *(const float4*)&Bs[kk][64 + nIdx*4];
            #pragma unroll
            for (int i = 0; i < 8; ++i)
                #pragma unroll
                for (int j = 0; j < 8; ++j)
                    acc[i][j] += af[i]*bf[j];
        }
    }

    #pragma unroll
    for (int j = 0; j < 8; ++j) {
        int n = n0 + nIdx*8 + j;
        int b = n / OUT3;
        int s = n - b*OUT3;
        float* o = out + ((size_t)b*256 + co0 + mIdx*8)*OUT3 + s;
        #pragma unroll
        for (int i = 0; i < 8; ++i)
            atomicAdd(o + (size_t)i*OUT3, acc[i][j]);
    }
}

// ---------------- squash primary capsules ----------------
__global__ __launch_bounds__(256)
void k_squash_u(const float* __restrict__ p_buf, const float* __restrict__ pbias,
                float* __restrict__ u)
{
    int g = blockIdx.x*256 + threadIdx.x;      // B*2048 = 4096
    int b = g >> 11;
    int i = g & 2047;
    int cap = i >> 6;
    int s   = i & 63;
    float vals[8];
    float sq = 0.f;
    #pragma unroll
    for (int c = 0; c < 8; ++c) {
        float x = p_buf[((size_t)(b*256) + cap*8 + c)*64 + s] + pbias[cap*8 + c];
        vals[c] = x;
        sq += x*x;
    }
    float scale = (sq / (1.f + sq)) / sqrtf(sq + 1e-8f);
    #pragma unroll
    for (int c = 0; c < 8; ++c) u[(size_t)g*8 + c] = vals[c]*scale;
}

// ---------------- routing ----------------
__global__ __launch_bounds__(256)
void k_route(const float* __restrict__ Wr, const float* __restrict__ u,
             float* __restrict__ s_buf)
{
    int j  = blockIdx.x;
    int i0 = blockIdx.y * 512;
    __shared__ float us[2*512*8];
    for (int idx = threadIdx.x; idx < 8192; idx += 256) {
        int b = idx >> 12;
        us[idx] = u[(size_t)b*16384 + (size_t)i0*8 + (idx & 4095)];
    }
    __syncthreads();
    int tid = threadIdx.x;
    int cc  = tid & 7;
    const float* Wj = Wr + (size_t)j*2048*512 + (size_t)i0*512;
    float a00 = 0.f, a01 = 0.f, a10 = 0.f, a11 = 0.f;
    for (int i = 0; i < 512; ++i) {
        float w0 = Wj[(size_t)i*512 + tid];
        float w1 = Wj[(size_t)i*512 + tid + 256];
        float u0 = us[i*8 + cc];
        float u1 = us[4096 + i*8 + cc];
        a00 += w0*u0; a01 += w1*u0; a10 += w0*u1; a11 += w1*u1;
    }
    __syncthreads();
    float* red = us;
    red[tid] = a00; red[256 + tid] = a01; red[512 + tid] = a10; red[768 + tid] = a11;
    __syncthreads();
    if (tid < 128) {
        int b = tid >> 6, d = tid & 63;
        const float* rb = red + b*512 + (d >> 5)*256 + (d & 31)*8;
        float s = 0.f;
        #pragma unroll
        for (int c2 = 0; c2 < 8; ++c2) s += rb[c2];
        atomicAdd(&s_buf[((size_t)b*50 + j)*64 + d], s * (1.0f/50.0f));
    }
}

// ---------------- squash v ----------------
__global__ __launch_bounds__(64)
void k_squash_v(const float* __restrict__ s_buf, float* __restrict__ v_buf)
{
    int row = blockIdx.x;
    int d   = threadIdx.x;
    float s  = s_buf[row*64 + d];
    float sq = s*s;
    #pragma unroll
    for (int o = 32; o > 0; o >>= 1) sq += __shfl_xor(sq, o);
    float scale = (sq / (1.f + sq)) / sqrtf(sq + 1e-8f);
    v_buf[row*64 + d] = s*scale;
}

// ---------------- dec1 -> fp16x2 channel-last limbs ----------------
__global__ __launch_bounds__(256)
void k_dec1(const float* __restrict__ v, const float* __restrict__ W,
            const float* __restrict__ bias, _Float16* __restrict__ d1cl)
{
    int g  = blockIdx.x*256 + threadIdx.x;  // 442368
    int co = g & 127;
    int t  = g >> 7;
    int o  = t % 1728;
    int b  = t / 1728;
    int ox = o / 144, oy = (o/12) % 12, oz = o % 12;
    int ix = ox/3, ka = ox - 3*ix;
    int iy = oy/3, kb = oy - 3*iy;
    int iz = oz/3, kc = oz - 3*iz;
    int widx = ka*9 + kb*3 + kc;
    int sidx = ix*16 + iy*4 + iz;
    float s = 0.f;
    for (int ci = 0; ci < 50; ++ci)
        s += v[((size_t)b*50 + ci)*64 + sidx] * W[((size_t)ci*128 + co)*27 + widx];
    float x = fmaxf(s + bias[co], 0.f);
    _Float16 a0, a1; split2(x, a0, a1);
    size_t base = (size_t)(b*1728 + o)*128 + co;
    d1cl[base]          = a0;
    d1cl[base + 442368] = a1;
}

// ---------------- dec2 MFMA: ConvTranspose3d(128->512, k3, s2, p1, op1), per co-half ----------------
__global__ __launch_bounds__(256, 3)
void k_dec2m(const _Float16* __restrict__ d1cl, const char* __restrict__ Wb,
             const float* __restrict__ bias, float* __restrict__ out, int coBase)
{
    extern __shared__ char lds[];
    const int tid = threadIdx.x;
    const int l   = tid & 63;
    const int w   = tid >> 6;
    const int wm  = w >> 1, wn = w & 1;
    const int n0  = blockIdx.x * 64;        // over 27648
    const int m   = blockIdx.y;             // 0..1 within half
    const int mG  = (coBase >> 7) + m;      // global m-tile 0..3

    const int q  = tid >> 6;
    const int nT = n0 + (tid & 63);
    const int bB = nT / 13824;
    const int so = nT - bB*13824;
    const int ox = so/576, oy = (so/24)%24, oz = so%24;

    int xo0, xo1, xo2, yo0, yo1, yo2, zo0, zo1, zo2;
    bool okx0, okx1, okx2, oky0, oky1, oky2, okz0, okz1, okz2;
    {
        int t;
        t = ox+1; okx0 = ((t&1)==0) && ((unsigned)t<24u); xo0 = okx0 ? (t>>1)*144 : 0;
        t = ox;   okx1 = ((t&1)==0) && ((unsigned)t<24u); xo1 = okx1 ? (t>>1)*144 : 0;
        t = ox-1; okx2 = ((t&1)==0) && ((unsigned)t<24u); xo2 = okx2 ? (t>>1)*144 : 0;
        t = oy+1; oky0 = ((t&1)==0) && ((unsigned)t<24u); yo0 = oky0 ? (t>>1)*12  : 0;
        t = oy;   oky1 = ((t&1)==0) && ((unsigned)t<24u); yo1 = oky1 ? (t>>1)*12  : 0;
        t = oy-1; oky2 = ((t&1)==0) && ((unsigned)t<24u); yo2 = oky2 ? (t>>1)*12  : 0;
        t = oz+1; okz0 = ((t&1)==0) && ((unsigned)t<24u); zo0 = okz0 ? (t>>1)     : 0;
        t = oz;   okz1 = ((t&1)==0) && ((unsigned)t<24u); zo1 = okz1 ? (t>>1)     : 0;
        t = oz-1; okz2 = ((t&1)==0) && ((unsigned)t<24u); zo2 = okz2 ? (t>>1)     : 0;
    }
    const int posBase = bB*1728;
    const int nRow = tid & 63;
    const int bw0 = 32768 + nRow*128 + ((q*32)      ^ ((nRow&7)<<4));
    const int bw1 = 32768 + nRow*128 + ((q*32 + 16) ^ ((nRow&7)<<4));

    const int swz = (l & 7) << 4;
    const int qo  = (l >> 4) << 4;
    const int plF = (l & 15)*128 + (qo ^ (swz & 0x30)) + (swz & 0x40);

    f32x4 acc0[4][2], acc1[4][2];
    const f32x4 zz = {0.f, 0.f, 0.f, 0.f};
    #pragma unroll
    for (int a = 0; a < 4; ++a)
        #pragma unroll
        for (int b = 0; b < 2; ++b) { acc0[a][b] = zz; acc1[a][b] = zz; }

    const h8 z8 = {};
    for (int c = 0; c < 54; ++c) {
        int kid = c >> 1;
        int kd = kid/9; int rm = kid - kd*9; int kh = rm/3; int kw = rm - kh*3;
        int xo = (kd==0) ? xo0 : ((kd==1) ? xo1 : xo2);
        int yo = (kh==0) ? yo0 : ((kh==1) ? yo1 : yo2);
        int zo = (kw==0) ? zo0 : ((kw==1) ? zo1 : zo2);
        bool okx = (kd==0) ? okx0 : ((kd==1) ? okx1 : okx2);
        bool oky = (kh==0) ? oky0 : ((kh==1) ? oky1 : oky2);
        bool okz = (kw==0) ? okz0 : ((kw==1) ? okz1 : okz2);
        bool ok = okx && oky && okz;
        const _Float16* src = d1cl + (size_t)(posBase + xo + yo + zo)*128
                                   + (c & 1)*64 + q*16;
        h8 b0a = *(const h8*)(src);
        h8 b0b = *(const h8*)(src + 8);
        h8 b1a = *(const h8*)(src + 442368);
        h8 b1b = *(const h8*)(src + 442368 + 8);

        __syncthreads();
        {
            const char* wsrc = (const char*)Wb + ((size_t)(mG*54 + c))*32768 + w*8192;
            #pragma unroll
            for (int i = 0; i < 8; ++i)
                gload16(wsrc + i*1024 + l*16, lds + w*8192 + i*1024);
        }
        *(h8*)(lds + bw0)         = ok ? b0a : z8;
        *(h8*)(lds + bw1)         = ok ? b0b : z8;
        *(h8*)(lds + 8192 + bw0)  = ok ? b1a : z8;
        *(h8*)(lds + 8192 + bw1)  = ok ? b1b : z8;
        __syncthreads();

        #pragma unroll
        for (int ks = 0; ks < 2; ++ks) {
            const int kx = ks ? 64 : 0;
            h8 af[2][4], bf[2][2];
            #pragma unroll
            for (int v = 0; v < 2; ++v) {
                #pragma unroll
                for (int mf = 0; mf < 4; ++mf)
                    af[v][mf] = *(const h8*)(lds + v*16384 + (wm*64 + mf*16)*128 + (plF ^ kx));
                #pragma unroll
                for (int nf = 0; nf < 2; ++nf)
                    bf[v][nf] = *(const h8*)(lds + 32768 + v*8192 + (wn*32 + nf*16)*128 + (plF ^ kx));
            }
            #pragma unroll
            for (int mf = 0; mf < 4; ++mf)
                #pragma unroll
                for (int nf = 0; nf < 2; ++nf) {
                    acc0[mf][nf] = __builtin_amdgcn_mfma_f32_16x16x32_f16(af[0][mf], bf[0][nf], acc0[mf][nf], 0,0,0);
                    acc1[mf][nf] = __builtin_amdgcn_mfma_f32_16x16x32_f16(af[0][mf], bf[1][nf], acc1[mf][nf], 0,0,0);
                    acc1[mf][nf] = __builtin_amdgcn_mfma_f32_16x16x32_f16(af[1][mf], bf[0][nf], acc1[mf][nf], 0,0,0);
                }
        }
    }

    const float s1 = 4.8828125e-04f;
    #pragma unroll
    for (int mf = 0; mf < 4; ++mf)
        #pragma unroll
        for (int nf = 0; nf < 2; ++nf) {
            f32x4 r = acc0[mf][nf] + s1*acc1[mf][nf];
            int coL = m*128 + wm*64 + mf*16 + ((l>>4)<<2);
            int coG = coBase + coL;
            int n   = n0 + wn*32 + nf*16 + (l&15);
            float4 v;
            v.x = fmaxf(r[0] + bias[coG + 0], 0.f);
            v.y = fmaxf(r[1] + bias[coG + 1], 0.f);
            v.z = fmaxf(r[2] + bias[coG + 2], 0.f);
            v.w = fmaxf(r[3] + bias[coG + 3], 0.f);
            *(float4*)(out + (size_t)n*256 + coL) = v;
        }
}

// ---------------- final gather (per co-half) ----------------
__global__ __launch_bounds__(256)
void k_gather(const float* __restrict__ d2h, const int* __restrict__ vid,
              float* __restrict__ out, int colOff)
{
    int g  = blockIdx.x*256 + threadIdx.x;   // B*P*64 float4 units
    int qq = g & 63;
    int bp = g >> 6;
    int v  = vid[bp];
    int b  = bp >> 13;
    float4 val = *(const float4*)&d2h[((size_t)(b*N3 + v))*256 + qq*4];
    *(float4*)&out[(size_t)bp*512 + colOff + qq*4] = val;
}

extern "C" void kernel_launch(void* const* d_in, const int* in_sizes, int n_in,
                              void* d_out, int out_size, void* d_ws, size_t ws_size,
                              hipStream_t stream)
{
    (void)in_sizes; (void)n_in; (void)out_size; (void)ws_size;
    const float* pcl  = (const float*)d_in[0];
    const float* feat = (const float*)d_in[1];
    const float* c1w  = (const float*)d_in[3];
    const float* c1b  = (const float*)d_in[4];
    const float* c2w  = (const float*)d_in[5];
    const float* c2b  = (const float*)d_in[6];
    const float* pw   = (const float*)d_in[7];
    const float* pb   = (const float*)d_in[8];
    const float* rw   = (const float*)d_in[9];
    const float* d1w  = (const float*)d_in[10];
    const float* d1b_ = (const float*)d_in[11];
    const float* d2w  = (const float*)d_in[12];
    const float* d2b  = (const float*)d_in[13];

    char* ws = (char*)d_ws;
    char*      Wb    = ws + WB_OFF;
    _Float16*  h1cl  = (_Float16*)(ws + H1CL_OFF);
    float*     meshS = (float*)(ws + MESHS_OFF);
    float*     h2    = (float*)(ws + H2_OFF);
    char*      Wb2   = ws + WB2_OFF;
    float*     d2h   = (float*)(ws + D2H_OFF);
    _Float16*  d1cl  = (_Float16*)(ws + D1CL_OFF);
    int*       vid   = (int*)(ws + VID_OFF);
    float*     p_buf = (float*)(ws + PBUF_OFF);
    float*     u_buf = (float*)(ws + UBUF_OFF);
    float*     s_buf = (float*)(ws + SBUF_OFF);
    float*     v_buf = (float*)(ws + VBUF_OFF);

    k_vid<<<dim3(B_), dim3(256), 0, stream>>>(pcl, vid);

    hipMemsetAsync(meshS, 0, 14155776, stream);
    k_scatter<<<dim3(8192), dim3(256), 0, stream>>>(feat, vid, meshS);

    // conv1
    k_splitw1<<<dim3(16000), dim3(256), 0, stream>>>(c1w, Wb);
    k_conv1<<<dim3(250, 2), dim3(256), 49152, stream>>>(meshS, Wb, c1b, h1cl);

    // conv2 in two K-halves (shared weight slot)
    k_splitw2<<<dim3(15872), dim3(256), 0, stream>>>(c2w, Wb, 0, 248);
    k_conv2<<<dim3(128, 2), dim3(256), 49152, stream>>>(h1cl, Wb, c2b, h2, 0, 248, 0);
    k_splitw2<<<dim3(16128), dim3(256), 0, stream>>>(c2w, Wb, 248, 252);
    k_conv2<<<dim3(128, 2), dim3(256), 49152, stream>>>(h1cl, Wb, c2b, h2, 248, 252, 1);

    // dec2 weight pre-split (region overlaps conv WB -> after conv2)
    k_splitwd2<<<dim3(6912), dim3(256), 0, stream>>>(d2w, Wb2);

    // primary caps: fp32 path, splitk 216
    hipMemsetAsync(p_buf, 0, 131072, stream);
    k_gemm_conv<256,9,2,16,4><<<dim3(1, 2, 216), dim3(256), 0, stream>>>(h2, pw, p_buf);
    k_squash_u<<<dim3(16), dim3(256), 0, stream>>>(p_buf, pb, u_buf);

    hipMemsetAsync(s_buf, 0, 25600, stream);
    k_route<<<dim3(50, 4), dim3(256), 0, stream>>>(rw, u_buf, s_buf);
    k_squash_v<<<dim3(100), dim3(64), 0, stream>>>(s_buf, v_buf);

    k_dec1<<<dim3(1728), dim3(256), 0, stream>>>(v_buf, d1w, d1b_, d1cl);

    k_dec2m<<<dim3(432, 2), dim3(256), 49152, stream>>>(d1cl, Wb2, d2b, d2h, 0);
    k_gather<<<dim3(4096), dim3(256), 0, stream>>>(d2h, vid, (float*)d_out, 0);
    k_dec2m<<<dim3(432, 2), dim3(256), 49152, stream>>>(d1cl, Wb2, d2b, d2h, 256);
    k_gather<<<dim3(4096), dim3(256), 0, stream>>>(d2h, vid, (float*)d_out, 256);
}